// Round 8
// baseline (507.145 us; speedup 1.0000x reference)
//
#include <hip/hip_runtime.h>
#include <cstdint>
#include <cmath>

typedef __attribute__((ext_vector_type(8))) short short8;
typedef __attribute__((ext_vector_type(4))) float floatx4;

#define DEV static __device__ __forceinline__

DEV float bf2f(uint16_t u) {
    union { uint32_t i; float f; } v; v.i = ((uint32_t)u) << 16; return v.f;
}
DEV uint16_t f2bf(float f) {
    union { float f; uint32_t i; } v; v.f = f;
    uint32_t r = (v.i + 0x7FFFu + ((v.i >> 16) & 1u)) >> 16;
    return (uint16_t)r;
}
DEV float swishf(float x) { return x / (1.f + __expf(-x)); }
DEV float geluf(float x) {
    const float c = 0.7978845608028654f;
    float t = tanhf(c * (x + 0.044715f * x * x * x));
    return 0.5f * x * (1.f + t);
}

#define CHUNK_E 8192
#define MAT_E   65536
#define APAD    264

// ---- Geometry (GEMM kernels): 512 blocks x 512 threads, 32-row tiles ----
// R7-proven structure. Round-8 deltas (inside same geometry):
//  (1) gemm_ks preloads ALL 16 B-fragments into named regs before the MFMA
//      loop (16 loads in flight; distinct array slots defeat copy-prop);
//      gemm2_ws uses a rolling 16-deep refill.
//  (2) split-K epilogue parallelized BY ROWS: each wave keeps the row-half
//      matching its K-half, dumps the other -> all 8 waves epilogue 16 rows
//      (R7: hi waves idle, lo did 32). Stores stay full-128B-line.
// 512 blocks -> 2 blocks/CU -> 16 waves/CU. Block: batch b = blk & 63 -> XCD b%8.

// ---- transpose+convert: W[K,N=256] fp32 -> packed chunks [kc][n][32] bf16 ----
struct TArg { const float* src[15]; };

__global__ __launch_bounds__(256) void tpose_k(TArg ta, uint16_t* __restrict__ arena) {
    int z = blockIdx.z;
    const float* src; uint16_t* dst;
    if (z == 0) {
        if (blockIdx.y) return;
        src = ta.src[0]; dst = arena;                            // w_enc [32,256]
    } else if (z <= 39) {
        int q = z - 1; int ti = q / 3, s = q % 3;
        src = ta.src[1 + ti] + (size_t)s * 65536;
        dst = arena + CHUNK_E + (size_t)(ti * 3 + s) * MAT_E;
    } else {
        src = ta.src[14]; dst = arena + CHUNK_E + (size_t)39 * MAT_E;   // hw1
    }
    int k0 = blockIdx.y << 5;
    int n0 = blockIdx.x << 6;
    __shared__ __align__(16) uint16_t tile[32][72];
    int t = threadIdx.x;
    {
        int r = t >> 3, c = (t & 7) << 3;
        const float* s0 = src + (size_t)(k0 + r) * 256 + n0 + c;
        float4 f0 = *(const float4*)s0;
        float4 f1 = *(const float4*)(s0 + 4);
        tile[r][c + 0] = f2bf(f0.x); tile[r][c + 1] = f2bf(f0.y);
        tile[r][c + 2] = f2bf(f0.z); tile[r][c + 3] = f2bf(f0.w);
        tile[r][c + 4] = f2bf(f1.x); tile[r][c + 5] = f2bf(f1.y);
        tile[r][c + 6] = f2bf(f1.z); tile[r][c + 7] = f2bf(f1.w);
    }
    __syncthreads();
    {
        int n = t >> 2, c = (t & 3) << 3;
        uint16_t tmp[8];
#pragma unroll
        for (int j = 0; j < 8; ++j) tmp[j] = tile[c + j][n];
        *(uint4*)&dst[(size_t)(k0 >> 5) * CHUNK_E + (size_t)(n0 + n) * 32 + c] = *(uint4*)tmp;
    }
}

// ---------------- shared pieces ----------------
struct SegArgs {
    const float* action; const float* obs;
    uint16_t *actb, *obsb, *xb, *bq, *bk, *bv, *bg, *brg;
    const float *ln0, *hb1, *hln, *hw2, *hb2;
    float* outp;
    float l2g[8];
};

enum { EP2_NONE = 0, EP2_SWIGLU = 1 };

// stage a 32x256 bf16 tile (global, row stride 256) into LDS [32][APAD]
DEV void stage32(const uint16_t* __restrict__ g, int m0, uint16_t* __restrict__ lds) {
    const int t = threadIdx.x;
#pragma unroll
    for (int j = 0; j < 2; ++j) {
        int u = t + (j << 9);             // 1024 short8 units
        int r = u >> 5, cc = (u & 31) << 3;
        *(short8*)(lds + (size_t)r * APAD + cc) =
            *(const short8*)(g + (size_t)(m0 + r) * 256 + cc);
    }
}

// ---- split-K single GEMM: 32x256 tile, K=256, RMS-family epilogue ----
// Wave (wc=w&3, kh=w>>2): cols [wc*64,+64), K-half kh. All 16 B-frags
// preloaded. Epilogue: wave keeps row-half kh (rows kh*16..+16), dumps the
// other to red; all 8 waves merge+rms+store their 16 rows, full-line stores.
// AL: A in LDS [32][APAD] else global stride 256 rows m0+...
// OG: also store to global Og. Ol (LDS [32][APAD]) always written.
// GELU: gelu(+bias); else residual (RL: LDS Rl else global Rg) add.
// Ends with __syncthreads() -> Ol immediately consumable.
template<bool AL, bool OG, bool RL, bool GELU>
DEV void gemm_ks(int m0, const uint16_t* __restrict__ A, const uint16_t* __restrict__ Wt,
                 uint16_t* __restrict__ Og, uint16_t* __restrict__ Ol,
                 const float* __restrict__ bias,
                 const uint16_t* __restrict__ Rg, const uint16_t* __restrict__ Rl,
                 const float* __restrict__ lnw,
                 float (&rowsum)[8][32], float (&red)[4][32][64])
{
    const int t = threadIdx.x;
    const int w = t >> 6, lane = t & 63, l16 = lane & 15, lg = lane >> 4;
    const int wc = w & 3, cb = wc << 6;
    const int kh = w >> 2;
    const int kbase = kh << 2;

    // preload ALL 16 B-fragments -> 16 global loads in flight
    short8 bF[4][4];
#pragma unroll
    for (int k2 = 0; k2 < 4; ++k2)
#pragma unroll
        for (int ct = 0; ct < 4; ++ct)
            bF[k2][ct] = *(const short8*)(Wt + (size_t)(kbase + k2) * CHUNK_E +
                                          (size_t)(cb + (ct << 4) + l16) * 32 + (lg << 3));

    floatx4 acc[2][4];
#pragma unroll
    for (int i = 0; i < 2; ++i)
#pragma unroll
        for (int j = 0; j < 4; ++j) acc[i][j] = (floatx4){0.f, 0.f, 0.f, 0.f};

#pragma unroll
    for (int k2 = 0; k2 < 4; ++k2) {
        const int kc = kbase + k2;
        short8 aF[2];
#pragma unroll
        for (int rt = 0; rt < 2; ++rt) {
            int row = (rt << 4) + l16;
            if constexpr (AL)
                aF[rt] = *(const short8*)(A + (size_t)row * APAD + (kc << 5) + (lg << 3));
            else
                aF[rt] = *(const short8*)(A + (size_t)(m0 + row) * 256 + (kc << 5) + (lg << 3));
        }
#pragma unroll
        for (int rt = 0; rt < 2; ++rt)
#pragma unroll
            for (int ct = 0; ct < 4; ++ct)
                acc[rt][ct] = __builtin_amdgcn_mfma_f32_16x16x32_bf16(
                    aF[rt], bF[k2][ct], acc[rt][ct], 0, 0, 0);
    }

    // cross-half exchange (wave-uniform branch; constant reg indices):
    // red idx 0..15 = row-half 0 partials (dumped by hi), 16..31 = half 1 (by lo)
    if (kh == 0) {
#pragma unroll
        for (int ct = 0; ct < 4; ++ct)
#pragma unroll
            for (int r = 0; r < 4; ++r)
                red[wc][16 | (ct << 2) | r][lane] = acc[1][ct][r];
    } else {
#pragma unroll
        for (int ct = 0; ct < 4; ++ct)
#pragma unroll
            for (int r = 0; r < 4; ++r)
                red[wc][(ct << 2) | r][lane] = acc[0][ct][r];
    }
    __syncthreads();

    // merge own row-half
    float v[4][4];
    if (kh == 0) {
#pragma unroll
        for (int ct = 0; ct < 4; ++ct)
#pragma unroll
            for (int r = 0; r < 4; ++r)
                v[ct][r] = acc[0][ct][r] + red[wc][(ct << 2) | r][lane];
    } else {
#pragma unroll
        for (int ct = 0; ct < 4; ++ct)
#pragma unroll
            for (int r = 0; r < 4; ++r)
                v[ct][r] = acc[1][ct][r] + red[wc][16 | (ct << 2) | r][lane];
    }

    const int rbase = kh << 4;
#pragma unroll
    for (int ct = 0; ct < 4; ++ct)
#pragma unroll
        for (int r = 0; r < 4; ++r) {
            int row = rbase + (lg << 2) + r;
            int col = cb + (ct << 4) + l16;
            float x = v[ct][r];
            if constexpr (GELU) {
                if (bias) x += bias[col];
                x = geluf(x);
            } else {
                if constexpr (RL) x += bf2f(Rl[(size_t)row * APAD + col]);
                else              x += bf2f(Rg[(size_t)(m0 + row) * 256 + col]);
            }
            v[ct][r] = x;
        }

#pragma unroll
    for (int r = 0; r < 4; ++r) {
        float p = 0.f;
#pragma unroll
        for (int ct = 0; ct < 4; ++ct) p += v[ct][r] * v[ct][r];
        p += __shfl_xor(p, 1, 64); p += __shfl_xor(p, 2, 64);
        p += __shfl_xor(p, 4, 64); p += __shfl_xor(p, 8, 64);
        int row = rbase + (lg << 2) + r;
        if (l16 == 0) rowsum[wc][row] = p;     // unique (wc,row) per wave
    }
    __syncthreads();
#pragma unroll
    for (int r = 0; r < 4; ++r) {
        int row = rbase + (lg << 2) + r;
        float tot = rowsum[0][row] + rowsum[1][row] + rowsum[2][row] + rowsum[3][row];
        float rn = rsqrtf(tot * (1.f / 256.f) + 1e-6f);
#pragma unroll
        for (int ct = 0; ct < 4; ++ct) {
            int col = cb + (ct << 4) + l16;
            uint16_t bb = f2bf(v[ct][r] * rn * lnw[col]);
            if constexpr (OG)
                Og[(size_t)(m0 + row) * 256 + col] = bb;
            Ol[(size_t)row * APAD + col] = bb;
        }
    }
    __syncthreads();
}

// ---- W-split dual GEMM: waves 0-3 -> W1, waves 4-7 -> W2, full K, 64 cols ----
// Rolling B preload: 16 fragments live; refill kc+4 right after kc's MFMAs.
// EP2_NONE: each wave group stores its matrix (full-line stores, no barrier).
// EP2_SWIGLU: W1=gate (lo), W2=up (hi); hi dumps to red, lo writes
//   swish(gate)*up -> LDS Ol. Internal barrier; NO trailing barrier.
template<int EPI, bool AL>
DEV void gemm2_ws(int m0, const uint16_t* __restrict__ A,
                  const uint16_t* __restrict__ W1, const uint16_t* __restrict__ W2,
                  uint16_t* __restrict__ O1, uint16_t* __restrict__ O2,
                  uint16_t* __restrict__ Ol, float (&red)[4][32][64])
{
    const int t = threadIdx.x;
    const int w = t >> 6, lane = t & 63, l16 = lane & 15, lg = lane >> 4;
    const int wc = w & 3, cb = wc << 6;
    const uint16_t* W = (w < 4) ? W1 : W2;
    const size_t wcol = (size_t)(cb + l16) * 32 + (lg << 3);

    floatx4 acc[2][4];
#pragma unroll
    for (int i = 0; i < 2; ++i)
#pragma unroll
        for (int j = 0; j < 4; ++j) acc[i][j] = (floatx4){0.f, 0.f, 0.f, 0.f};

    // preload kc 0..3 (16 loads in flight)
    short8 bF[4][4];
#pragma unroll
    for (int k2 = 0; k2 < 4; ++k2)
#pragma unroll
        for (int ct = 0; ct < 4; ++ct)
            bF[k2][ct] = *(const short8*)(W + (size_t)k2 * CHUNK_E + wcol +
                                          (size_t)(ct << 4) * 32);

#pragma unroll
    for (int k2 = 0; k2 < 4; ++k2) {
        short8 aF[2];
#pragma unroll
        for (int rt = 0; rt < 2; ++rt) {
            int row = (rt << 4) + l16;
            if constexpr (AL)
                aF[rt] = *(const short8*)(A + (size_t)row * APAD + (k2 << 5) + (lg << 3));
            else
                aF[rt] = *(const short8*)(A + (size_t)(m0 + row) * 256 + (k2 << 5) + (lg << 3));
        }
#pragma unroll
        for (int rt = 0; rt < 2; ++rt)
#pragma unroll
            for (int ct = 0; ct < 4; ++ct)
                acc[rt][ct] = __builtin_amdgcn_mfma_f32_16x16x32_bf16(
                    aF[rt], bF[k2][ct], acc[rt][ct], 0, 0, 0);
        // refill slot k2 with kc = k2+4 (issues while later MFMAs run)
#pragma unroll
        for (int ct = 0; ct < 4; ++ct)
            bF[k2][ct] = *(const short8*)(W + (size_t)(k2 + 4) * CHUNK_E + wcol +
                                          (size_t)(ct << 4) * 32);
    }
#pragma unroll
    for (int k2 = 0; k2 < 4; ++k2) {
        const int kc = k2 + 4;
        short8 aF[2];
#pragma unroll
        for (int rt = 0; rt < 2; ++rt) {
            int row = (rt << 4) + l16;
            if constexpr (AL)
                aF[rt] = *(const short8*)(A + (size_t)row * APAD + (kc << 5) + (lg << 3));
            else
                aF[rt] = *(const short8*)(A + (size_t)(m0 + row) * 256 + (kc << 5) + (lg << 3));
        }
#pragma unroll
        for (int rt = 0; rt < 2; ++rt)
#pragma unroll
            for (int ct = 0; ct < 4; ++ct)
                acc[rt][ct] = __builtin_amdgcn_mfma_f32_16x16x32_bf16(
                    aF[rt], bF[k2][ct], acc[rt][ct], 0, 0, 0);
    }

    if constexpr (EPI == EP2_NONE) {
        uint16_t* O = (w < 4) ? O1 : O2;
#pragma unroll
        for (int rt = 0; rt < 2; ++rt)
#pragma unroll
            for (int ct = 0; ct < 4; ++ct)
#pragma unroll
                for (int r = 0; r < 4; ++r) {
                    int row = (rt << 4) + (lg << 2) + r;
                    int col = cb + (ct << 4) + l16;
                    O[(size_t)(m0 + row) * 256 + col] = f2bf(acc[rt][ct][r]);
                }
    } else {  // EP2_SWIGLU
        if (w >= 4) {
#pragma unroll
            for (int rt = 0; rt < 2; ++rt)
#pragma unroll
                for (int ct = 0; ct < 4; ++ct)
#pragma unroll
                    for (int r = 0; r < 4; ++r)
                        red[wc][(rt << 4) | (ct << 2) | r][lane] = acc[rt][ct][r];
        }
        __syncthreads();
        if (w < 4) {
#pragma unroll
            for (int rt = 0; rt < 2; ++rt)
#pragma unroll
                for (int ct = 0; ct < 4; ++ct)
#pragma unroll
                    for (int r = 0; r < 4; ++r) {
                        int row = (rt << 4) + (lg << 2) + r;
                        int col = cb + (ct << 4) + l16;
                        float up = red[wc][(rt << 4) | (ct << 2) | r][lane];
                        Ol[(size_t)row * APAD + col] = f2bf(swishf(acc[rt][ct][r]) * up);
                    }
        }
    }
}

// ---- enc GEMM (K=32): R2's 8-wave x 32-col path, gelu+rms epilogue ----
DEV void gemm_enc(int m0, const uint16_t* __restrict__ A, const uint16_t* __restrict__ Wt,
                  uint16_t* __restrict__ Og, uint16_t* __restrict__ Ol,
                  const float* __restrict__ lnw, float (&rowsum)[8][32])
{
    const int t = threadIdx.x;
    const int w = t >> 6, lane = t & 63, l16 = lane & 15, lg = lane >> 4;

    floatx4 acc[2][2];
#pragma unroll
    for (int i = 0; i < 2; ++i)
#pragma unroll
        for (int j = 0; j < 2; ++j) acc[i][j] = (floatx4){0.f, 0.f, 0.f, 0.f};

    short8 aF[2], bF[2];
#pragma unroll
    for (int rt = 0; rt < 2; ++rt)
        aF[rt] = *(const short8*)(A + (size_t)((rt << 4) + l16) * 40 + (lg << 3));
#pragma unroll
    for (int ct = 0; ct < 2; ++ct)
        bF[ct] = *(const short8*)(Wt + (size_t)((w << 5) + (ct << 4) + l16) * 32 + (lg << 3));
#pragma unroll
    for (int rt = 0; rt < 2; ++rt)
#pragma unroll
        for (int ct = 0; ct < 2; ++ct)
            acc[rt][ct] = __builtin_amdgcn_mfma_f32_16x16x32_bf16(
                aF[rt], bF[ct], acc[rt][ct], 0, 0, 0);

    float v[2][2][4];
#pragma unroll
    for (int rt = 0; rt < 2; ++rt)
#pragma unroll
        for (int ct = 0; ct < 2; ++ct)
#pragma unroll
            for (int r = 0; r < 4; ++r)
                v[rt][ct][r] = geluf(acc[rt][ct][r]);

#pragma unroll
    for (int rt = 0; rt < 2; ++rt)
#pragma unroll
        for (int r = 0; r < 4; ++r) {
            float p = v[rt][0][r] * v[rt][0][r] + v[rt][1][r] * v[rt][1][r];
            p += __shfl_xor(p, 1, 64); p += __shfl_xor(p, 2, 64);
            p += __shfl_xor(p, 4, 64); p += __shfl_xor(p, 8, 64);
            int row = (rt << 4) + (lg << 2) + r;
            if (l16 == 0) rowsum[w][row] = p;
        }
    __syncthreads();
#pragma unroll
    for (int rt = 0; rt < 2; ++rt)
#pragma unroll
        for (int r = 0; r < 4; ++r) {
            int row = (rt << 4) + (lg << 2) + r;
            float tot = rowsum[0][row] + rowsum[1][row] + rowsum[2][row] + rowsum[3][row]
                      + rowsum[4][row] + rowsum[5][row] + rowsum[6][row] + rowsum[7][row];
            float rn = rsqrtf(tot * (1.f / 256.f) + 1e-6f);
#pragma unroll
            for (int ct = 0; ct < 2; ++ct) {
                int col = (w << 5) + (ct << 4) + l16;
                uint16_t bb = f2bf(v[rt][ct][r] * rn * lnw[col]);
                Og[(size_t)(m0 + row) * 256 + col] = bb;
                Ol[(size_t)row * APAD + col] = bb;
            }
        }
    __syncthreads();
}

DEV int rowbase(int blk) { return (blk & 63) * 256 + (blk >> 6) * 32; }

// ---------------- segment kernels (512 blocks x 512 threads) ----------------

__global__ __launch_bounds__(512, 4) void seg0_k(SegArgs sa, const uint16_t* __restrict__ wenc,
                                                 const uint16_t* __restrict__ wq,
                                                 const uint16_t* __restrict__ wk,
                                                 const uint16_t* __restrict__ wv,
                                                 const uint16_t* __restrict__ wg)
{
    __shared__ float rowsum[8][32];
    __shared__ float red[4][32][64];
    __shared__ __align__(16) uint16_t actS[32][40];
    __shared__ __align__(16) uint16_t T0[32][APAD];
    const int t = threadIdx.x;
    const int m0 = rowbase(blockIdx.x);
    if (t < 256) {
        int r = t >> 3, c = (t & 7) << 2;
        float4 f = *(const float4*)(sa.action + (size_t)(m0 + r) * 32 + c);
        uint16_t tmp[4] = { f2bf(f.x), f2bf(f.y), f2bf(f.z), f2bf(f.w) };
        *(uint2*)&actS[r][c] = *(uint2*)tmp;
    }
    {
        const float4* ob = (const float4*)sa.obs + (size_t)m0 * 64;
        uint2* od = (uint2*)sa.obsb + (size_t)m0 * 64;
#pragma unroll
        for (int j = 0; j < 4; ++j) {
            float4 f = ob[(j << 9) + t];
            uint16_t tmp[4] = { f2bf(f.x), f2bf(f.y), f2bf(f.z), f2bf(f.w) };
            od[(j << 9) + t] = *(uint2*)tmp;
        }
    }
    __syncthreads();
    // x = rms(gelu(action@wenc)) -> LDS T0 + global xb (g1's ln1 residual)
    gemm_enc(m0, &actS[0][0], wenc, sa.xb, &T0[0][0], sa.ln0, rowsum);
    gemm2_ws<EP2_NONE, true>(m0, &T0[0][0], wq, wk, sa.bq, sa.bk, nullptr, red);
    gemm2_ws<EP2_NONE, true>(m0, &T0[0][0], wv, wg, sa.bv, sa.bg, nullptr, red);
}

__global__ __launch_bounds__(512, 4) void attn_k(SegArgs sa, const float* __restrict__ gns,
                                                 const float* __restrict__ gnb)
{
    __shared__ __align__(16) uint16_t QS[256][40];
    __shared__ __align__(16) uint16_t Ks[256][40];
    __shared__ __align__(16) uint16_t Vt[32][264];
    const int b = blockIdx.x & 63, h = blockIdx.x >> 6;
    const float l2g = sa.l2g[h];
    const int t = threadIdx.x, w = t >> 6, lane = t & 63, l16 = lane & 15, lg = lane >> 4;
    const size_t base = ((size_t)b * 256) * 256 + (size_t)h * 32;
    const uint16_t *q = sa.bq, *kbuf = sa.bk, *vbuf = sa.bv, *g = sa.bg;
    uint16_t* out = sa.brg;

    if (t < 256) {
        const uint4* qr = (const uint4*)(q + base + (size_t)t * 256);
        *(uint4*)&QS[t][0] = qr[0]; *(uint4*)&QS[t][8] = qr[1];
        *(uint4*)&QS[t][16] = qr[2]; *(uint4*)&QS[t][24] = qr[3];
        const uint4* kr = (const uint4*)(kbuf + base + (size_t)t * 256);
        *(uint4*)&Ks[t][0] = kr[0]; *(uint4*)&Ks[t][8] = kr[1];
        *(uint4*)&Ks[t][16] = kr[2]; *(uint4*)&Ks[t][24] = kr[3];
    } else {
        int c = t - 256;
        union { uint4 v4[4]; uint16_t u[32]; } vv;
        const uint4* vr = (const uint4*)(vbuf + base + (size_t)c * 256);
        vv.v4[0] = vr[0]; vv.v4[1] = vr[1]; vv.v4[2] = vr[2]; vv.v4[3] = vr[3];
#pragma unroll
        for (int d = 0; d < 32; ++d) Vt[d][c] = vv.u[d];
    }
    __syncthreads();

    // balanced strips: wave w owns 16-row half-strips {w, 15-w} (work sums to 9)
    const int iA = w, iB = 15 - w;
    short8 qFA = *(const short8*)&QS[(iA << 4) + l16][lg << 3];
    short8 qFB = *(const short8*)&QS[(iB << 4) + l16][lg << 3];

    const float invsq = 0.17677669529663687f;

    floatx4 raccA[2], raccB[2];
    raccA[0] = (floatx4){0,0,0,0}; raccA[1] = (floatx4){0,0,0,0};
    raccB[0] = (floatx4){0,0,0,0}; raccB[1] = (floatx4){0,0,0,0};

    auto do_strip = [&](int si, short8 qF, floatx4 (&racc)[2]) {
        const int jtmax = ((si << 4) + 15) >> 5;
        for (int jt = 0; jt <= jtmax; ++jt) {
            const int j0 = jt << 5;
            floatx4 sacc[2];
            sacc[0] = (floatx4){0,0,0,0}; sacc[1] = (floatx4){0,0,0,0};
            short8 kF[2];
#pragma unroll
            for (int ct = 0; ct < 2; ++ct)
                kF[ct] = *(const short8*)&Ks[j0 + (ct << 4) + l16][lg << 3];
#pragma unroll
            for (int ct = 0; ct < 2; ++ct)
                sacc[ct] = __builtin_amdgcn_mfma_f32_16x16x32_bf16(
                    qF, kF[ct], sacc[ct], 0, 0, 0);
#pragma unroll
            for (int ct = 0; ct < 2; ++ct)
#pragma unroll
                for (int r = 0; r < 4; ++r) {
                    int row16 = (lg << 2) + r;
                    int i = (si << 4) + row16;
                    int j = j0 + (ct << 4) + l16;
                    float svv = 0.f;
                    if (i >= j)
                        svv = sacc[ct][r] * invsq *
                              exp2f((float)((i >> 3) - (j >> 3)) * l2g);
                    QS[(si << 4) + row16][(ct << 4) + l16] = f2bf(svv);
                }
            short8 vF[2];
#pragma unroll
            for (int ct = 0; ct < 2; ++ct)
                vF[ct] = *(const short8*)&Vt[(ct << 4) + l16][j0 + (lg << 3)];
            short8 sF = *(const short8*)&QS[(si << 4) + l16][lg << 3];
#pragma unroll
            for (int ct = 0; ct < 2; ++ct)
                racc[ct] = __builtin_amdgcn_mfma_f32_16x16x32_bf16(
                    sF, vF[ct], racc[ct], 0, 0, 0);
        }
    };
    do_strip(iA, qFA, raccA);
    do_strip(iB, qFB, raccB);

    auto epi = [&](int si, floatx4 (&racc)[2]) {
#pragma unroll
        for (int r = 0; r < 4; ++r) {
            float v0 = racc[0][r], v1 = racc[1][r];
            float s1 = v0 + v1, s2 = v0 * v0 + v1 * v1;
            s1 += __shfl_xor(s1, 1, 64); s2 += __shfl_xor(s2, 1, 64);
            s1 += __shfl_xor(s1, 2, 64); s2 += __shfl_xor(s2, 2, 64);
            s1 += __shfl_xor(s1, 4, 64); s2 += __shfl_xor(s2, 4, 64);
            s1 += __shfl_xor(s1, 8, 64); s2 += __shfl_xor(s2, 8, 64);
            float mu = s1 * (1.f / 32.f);
            float var = s2 * (1.f / 32.f) - mu * mu;
            float rstd = rsqrtf(var + 1e-5f);
            int srow = (si << 4) + (lg << 2) + r;
            size_t obase = ((size_t)b * 256 + srow) * 256 + (size_t)h * 32;
#pragma unroll
            for (int ct = 0; ct < 2; ++ct) {
                int d = (ct << 4) + l16;
                float x = ct ? v1 : v0;
                float y = (x - mu) * rstd * gns[h * 32 + d] + gnb[h * 32 + d];
                float gv = swishf(bf2f(g[obase + d]));
                out[obase + d] = f2bf(y * gv);
            }
        }
    };
    epi(iA, raccA);
    epi(iB, raccB);
}

__global__ __launch_bounds__(512, 4) void g1_k(SegArgs sa,
    const uint16_t* __restrict__ wo, const float* __restrict__ ln1,
    const uint16_t* __restrict__ wq, const uint16_t* __restrict__ wk,
    const uint16_t* __restrict__ wv, const uint16_t* __restrict__ wg)
{
    __shared__ float rowsum[8][32];
    __shared__ float red[4][32][64];
    __shared__ __align__(16) uint16_t T0[32][APAD];
    __shared__ __align__(16) uint16_t T1[32][APAD];
    const int m0 = rowbase(blockIdx.x);
    stage32(sa.brg, m0, &T1[0][0]);
    __syncthreads();
    // x1 = rms(x + brg@wo) -> LDS T0 (consumed only by wk/wv)
    gemm_ks<true, false, false, false>(m0, &T1[0][0], wo,
        nullptr, &T0[0][0], nullptr, sa.xb, nullptr, ln1, rowsum, red);
    // T1 free (its reads finished before gemm_ks's exchange barrier): stage obsb
    stage32(sa.obsb, m0, &T1[0][0]);
    gemm2_ws<EP2_NONE, true>(m0, &T0[0][0], wk, wv, sa.bk, sa.bv, nullptr, red);
    __syncthreads();
    gemm2_ws<EP2_NONE, true>(m0, &T1[0][0], wq, wg, sa.bq, sa.bg, nullptr, red);
}

__global__ __launch_bounds__(512, 4) void g2_k(SegArgs sa,
    const uint16_t* __restrict__ wo, const float* __restrict__ ln2,
    const uint16_t* __restrict__ wswg, const uint16_t* __restrict__ wsw1,
    const uint16_t* __restrict__ wsw2, const float* __restrict__ ln3,
    const uint16_t* __restrict__ nwq, const uint16_t* __restrict__ nwk,
    const uint16_t* __restrict__ nwv, const uint16_t* __restrict__ nwg)
{
    __shared__ float rowsum[8][32];
    __shared__ float red[4][32][64];
    __shared__ __align__(16) uint16_t T0[32][APAD];
    __shared__ __align__(16) uint16_t T1[32][APAD];
    const int m0 = rowbase(blockIdx.x);
    stage32(sa.brg, m0, &T1[0][0]);
    __syncthreads();
    // x2 = rms(obs + brg@wo) -> LDS T0
    gemm_ks<true, false, false, false>(m0, &T1[0][0], wo,
        nullptr, &T0[0][0], nullptr, sa.obsb, nullptr, ln2, rowsum, red);
    // swiglu gate*up -> LDS T1 (gate=lo/swg, up=hi/sw1 via red); no trailing barrier
    gemm2_ws<EP2_SWIGLU, true>(m0, &T0[0][0], wswg, wsw1, nullptr, nullptr, &T1[0][0], red);
    __syncthreads();   // T1 visible to all waves
    // x3 = rms(x2 + T1@sw2): T0 in-place (resid rows read by the owning wave
    // pre-rowsum-barrier, rewritten post-barrier by the same thread).
    // Global xb copy for next g1 / head.
    gemm_ks<true, true, true, false>(m0, &T1[0][0], wsw2,
        sa.xb, &T0[0][0], nullptr, nullptr, &T0[0][0], ln3, rowsum, red);
    if (nwq) {
        gemm2_ws<EP2_NONE, true>(m0, &T0[0][0], nwq, nwk, sa.bq, sa.bk, nullptr, red);
        gemm2_ws<EP2_NONE, true>(m0, &T0[0][0], nwv, nwg, sa.bv, sa.bg, nullptr, red);
    }
}

__global__ __launch_bounds__(512, 4) void head_k(SegArgs sa, const uint16_t* __restrict__ hw1t)
{
    __shared__ float rowsum[8][32];
    __shared__ float red[4][32][64];   // reused as w2s after the GEMM
    __shared__ __align__(16) uint16_t T0[32][APAD];
    const int t = threadIdx.x;
    const int m0 = rowbase(blockIdx.x);
    // h = rms(gelu(x@hw1+hb1)) -> LDS T0 (A = xb global)
    gemm_ks<false, false, false, true>(m0, sa.xb, hw1t,
        nullptr, &T0[0][0], sa.hb1, nullptr, nullptr, sa.hln, rowsum, red);
    float* w2s = &red[0][0][0];        // red dead after gemm_ks's final barrier
#pragma unroll
    for (int j = 0; j < 16; ++j) w2s[(j << 9) + t] = sa.hw2[(j << 9) + t];
    __syncthreads();
    {
        int n = t & 31, rs = t >> 5;    // rs 0..15
#pragma unroll
        for (int rr = 0; rr < 2; ++rr) {
            int lrow = (rr << 4) + rs;
            float a0 = sa.hb2[n];
#pragma unroll 8
            for (int kk = 0; kk < 256; ++kk)
                a0 += bf2f(T0[lrow][kk]) * w2s[kk * 32 + n];
            sa.outp[(size_t)(m0 + lrow) * 32 + n] = a0;
        }
    }
}

// ---------------- host ----------------
extern "C" void kernel_launch(void* const* d_in, const int* in_sizes, int n_in,
                              void* d_out, int out_size, void* d_ws, size_t ws_size,
                              hipStream_t stream)
{
    const float* action = (const float*)d_in[0];
    const float* obs    = (const float*)d_in[1];
    const float* w_enc  = (const float*)d_in[2];
    const float* ln0    = (const float*)d_in[3];
    const float* wq1 = (const float*)d_in[4];
    const float* wk1 = (const float*)d_in[5];
    const float* wv1 = (const float*)d_in[6];
    const float* wg1 = (const float*)d_in[7];
    const float* wo1 = (const float*)d_in[8];
    const float* gns1 = (const float*)d_in[9];
    const float* gnb1 = (const float*)d_in[10];
    const float* ln1  = (const float*)d_in[11];
    const float* wq2 = (const float*)d_in[12];
    const float* wk2 = (const float*)d_in[13];
    const float* wv2 = (const float*)d_in[14];
    const float* wg2 = (const float*)d_in[15];
    const float* wo2 = (const float*)d_in[16];
    const float* gns2 = (const float*)d_in[17];
    const float* gnb2 = (const float*)d_in[18];
    const float* ln2  = (const float*)d_in[19];
    const float* swgp = (const float*)d_in[20];
    const float* sw1p = (const float*)d_in[21];
    const float* sw2p = (const float*)d_in[22];
    const float* ln3  = (const float*)d_in[23];
    const float* hw1  = (const float*)d_in[24];
    const float* hb1  = (const float*)d_in[25];
    const float* hln  = (const float*)d_in[26];
    const float* hw2  = (const float*)d_in[27];
    const float* hb2  = (const float*)d_in[28];

    char* ws = (char*)d_ws;
    uint16_t* wt   = (uint16_t*)(ws + 0);
    uint16_t* actb = (uint16_t*)(ws + 6291456);
    uint16_t* obsb = (uint16_t*)(ws + 7340032);
    uint16_t* xb   = (uint16_t*)(ws + 15728640);
    uint16_t* bq   = (uint16_t*)(ws + 24117248);
    uint16_t* bk   = (uint16_t*)(ws + 32505856);
    uint16_t* bv   = (uint16_t*)(ws + 40894464);
    uint16_t* bg   = (uint16_t*)(ws + 49283072);
    uint16_t* brg  = (uint16_t*)(ws + 57671680);

    uint16_t* wtenc = wt;
    uint16_t* hw1t  = wt + CHUNK_E + (size_t)39 * MAT_E;
    auto WTp = [&](int ti, int s) { return wt + CHUNK_E + (size_t)(ti * 3 + s) * MAT_E; };

    TArg ta;
    ta.src[0] = w_enc;
    ta.src[1] = wq1;  ta.src[2] = wk1;  ta.src[3] = wv1;  ta.src[4] = wg1;  ta.src[5] = wo1;
    ta.src[6] = wq2;  ta.src[7] = wk2;  ta.src[8] = wv2;  ta.src[9] = wg2;  ta.src[10] = wo2;
    ta.src[11] = swgp; ta.src[12] = sw1p; ta.src[13] = sw2p; ta.src[14] = hw1;
    tpose_k<<<dim3(4, 8, 41), 256, 0, stream>>>(ta, wt);

    SegArgs sa;
    sa.action = action; sa.obs = obs;
    sa.actb = actb; sa.obsb = obsb; sa.xb = xb;
    sa.bq = bq; sa.bk = bk; sa.bv = bv; sa.bg = bg; sa.brg = brg;
    sa.ln0 = ln0; sa.hb1 = hb1; sa.hln = hln; sa.hw2 = hw2; sa.hb2 = hb2;
    sa.outp = (float*)d_out;
    {
        const double a = log(1.0 / 32.0), bb = log(1.0 / 512.0);
        for (int hh = 0; hh < 8; ++hh) {
            double lg = a + (bb - a) * hh / 7.0;
            double gam = 1.0 - exp(lg);
            sa.l2g[hh] = (float)(log(gam) / log(2.0));
        }
    }

    dim3 GB(512), TB(512);
    seg0_k<<<GB, TB, 0, stream>>>(sa, wtenc, WTp(0, 0), WTp(1, 0), WTp(2, 0), WTp(3, 0));
    for (int b3 = 0; b3 < 3; ++b3) {
        attn_k<<<GB, TB, 0, stream>>>(sa, gns1 + b3 * 256, gnb1 + b3 * 256);
        g1_k<<<GB, TB, 0, stream>>>(sa, WTp(4, b3), ln1 + b3 * 256,
                                    WTp(5, b3), WTp(6, b3), WTp(7, b3), WTp(8, b3));
        attn_k<<<GB, TB, 0, stream>>>(sa, gns2 + b3 * 256, gnb2 + b3 * 256);
        g2_k<<<GB, TB, 0, stream>>>(sa, WTp(9, b3), ln2 + b3 * 256,
                                    WTp(10, b3), WTp(11, b3), WTp(12, b3), ln3 + b3 * 256,
                                    b3 < 2 ? WTp(0, b3 + 1) : nullptr,
                                    b3 < 2 ? WTp(1, b3 + 1) : nullptr,
                                    b3 < 2 ? WTp(2, b3 + 1) : nullptr,
                                    b3 < 2 ? WTp(3, b3 + 1) : nullptr);
    }
    head_k<<<GB, TB, 0, stream>>>(sa, hw1t);
}

// Round 9
// 499.308 us; speedup vs baseline: 1.0157x; 1.0157x over previous
//
#include <hip/hip_runtime.h>
#include <cstdint>
#include <cmath>

typedef __attribute__((ext_vector_type(8))) short short8;
typedef __attribute__((ext_vector_type(4))) float floatx4;

#define DEV static __device__ __forceinline__

DEV float bf2f(uint16_t u) {
    union { uint32_t i; float f; } v; v.i = ((uint32_t)u) << 16; return v.f;
}
DEV uint16_t f2bf(float f) {
    union { float f; uint32_t i; } v; v.f = f;
    uint32_t r = (v.i + 0x7FFFu + ((v.i >> 16) & 1u)) >> 16;
    return (uint16_t)r;
}
DEV float swishf(float x) { return x / (1.f + __expf(-x)); }
DEV float geluf(float x) {
    const float c = 0.7978845608028654f;
    float t = tanhf(c * (x + 0.044715f * x * x * x));
    return 0.5f * x * (1.f + t);
}

#define CHUNK_E 8192
#define MAT_E   65536
#define APAD    264

// ---- Geometry (GEMM kernels): 512 blocks x 512 threads, 32-row tiles ----
// R7-proven structure + R9 delta: split-K epilogue parallelized BY ROWS
// (each wave keeps the row-half matching its K-half, dumps the other; all
// 8 waves epilogue 16 rows — R7 had hi waves idle while lo did 32).
// B-load schedule is R7's compiler-scheduled form: R8's explicit 16-deep
// preload SPILLED (VGPR stuck at 64; FETCH/WRITE doubled via scratch).
// 512 blocks -> 2 blocks/CU -> 16 waves/CU. Block: batch b = blk & 63 -> XCD b%8.

// ---- transpose+convert: W[K,N=256] fp32 -> packed chunks [kc][n][32] bf16 ----
struct TArg { const float* src[15]; };

__global__ __launch_bounds__(256) void tpose_k(TArg ta, uint16_t* __restrict__ arena) {
    int z = blockIdx.z;
    const float* src; uint16_t* dst;
    if (z == 0) {
        if (blockIdx.y) return;
        src = ta.src[0]; dst = arena;                            // w_enc [32,256]
    } else if (z <= 39) {
        int q = z - 1; int ti = q / 3, s = q % 3;
        src = ta.src[1 + ti] + (size_t)s * 65536;
        dst = arena + CHUNK_E + (size_t)(ti * 3 + s) * MAT_E;
    } else {
        src = ta.src[14]; dst = arena + CHUNK_E + (size_t)39 * MAT_E;   // hw1
    }
    int k0 = blockIdx.y << 5;
    int n0 = blockIdx.x << 6;
    __shared__ __align__(16) uint16_t tile[32][72];
    int t = threadIdx.x;
    {
        int r = t >> 3, c = (t & 7) << 3;
        const float* s0 = src + (size_t)(k0 + r) * 256 + n0 + c;
        float4 f0 = *(const float4*)s0;
        float4 f1 = *(const float4*)(s0 + 4);
        tile[r][c + 0] = f2bf(f0.x); tile[r][c + 1] = f2bf(f0.y);
        tile[r][c + 2] = f2bf(f0.z); tile[r][c + 3] = f2bf(f0.w);
        tile[r][c + 4] = f2bf(f1.x); tile[r][c + 5] = f2bf(f1.y);
        tile[r][c + 6] = f2bf(f1.z); tile[r][c + 7] = f2bf(f1.w);
    }
    __syncthreads();
    {
        int n = t >> 2, c = (t & 3) << 3;
        uint16_t tmp[8];
#pragma unroll
        for (int j = 0; j < 8; ++j) tmp[j] = tile[c + j][n];
        *(uint4*)&dst[(size_t)(k0 >> 5) * CHUNK_E + (size_t)(n0 + n) * 32 + c] = *(uint4*)tmp;
    }
}

// ---------------- shared pieces ----------------
struct SegArgs {
    const float* action; const float* obs;
    uint16_t *actb, *obsb, *xb, *bq, *bk, *bv, *bg, *brg;
    const float *ln0, *hb1, *hln, *hw2, *hb2;
    float* outp;
    float l2g[8];
};

enum { EP2_NONE = 0, EP2_SWIGLU = 1 };

// stage a 32x256 bf16 tile (global, row stride 256) into LDS [32][APAD]
DEV void stage32(const uint16_t* __restrict__ g, int m0, uint16_t* __restrict__ lds) {
    const int t = threadIdx.x;
#pragma unroll
    for (int j = 0; j < 2; ++j) {
        int u = t + (j << 9);             // 1024 short8 units
        int r = u >> 5, cc = (u & 31) << 3;
        *(short8*)(lds + (size_t)r * APAD + cc) =
            *(const short8*)(g + (size_t)(m0 + r) * 256 + cc);
    }
}

// ---- split-K single GEMM: 32x256 tile, K=256, RMS-family epilogue ----
// Wave (wc=w&3, kh=w>>2): cols [wc*64,+64), K-half kh. B loads inside the
// unrolled k2 loop (compiler-scheduled — R7 form, no spill).
// Epilogue: wave keeps row-half kh (rows kh*16..+16), dumps the other to
// red; all 8 waves merge+rms+store 16 rows each, full-128B-line stores.
// AL: A in LDS [32][APAD] else global stride 256 rows m0+...
// OG: also store to global Og. Ol (LDS [32][APAD]) always written.
// GELU: gelu(+bias); else residual (RL: LDS Rl else global Rg) add.
// Ends with __syncthreads() -> Ol immediately consumable.
template<bool AL, bool OG, bool RL, bool GELU>
DEV void gemm_ks(int m0, const uint16_t* __restrict__ A, const uint16_t* __restrict__ Wt,
                 uint16_t* __restrict__ Og, uint16_t* __restrict__ Ol,
                 const float* __restrict__ bias,
                 const uint16_t* __restrict__ Rg, const uint16_t* __restrict__ Rl,
                 const float* __restrict__ lnw,
                 float (&rowsum)[8][32], float (&red)[4][32][64])
{
    const int t = threadIdx.x;
    const int w = t >> 6, lane = t & 63, l16 = lane & 15, lg = lane >> 4;
    const int wc = w & 3, cb = wc << 6;
    const int kh = w >> 2;
    const int kbase = kh << 2;

    floatx4 acc[2][4];
#pragma unroll
    for (int i = 0; i < 2; ++i)
#pragma unroll
        for (int j = 0; j < 4; ++j) acc[i][j] = (floatx4){0.f, 0.f, 0.f, 0.f};

#pragma unroll
    for (int k2 = 0; k2 < 4; ++k2) {
        const int kc = kbase + k2;
        short8 aF[2], bF[4];
#pragma unroll
        for (int rt = 0; rt < 2; ++rt) {
            int row = (rt << 4) + l16;
            if constexpr (AL)
                aF[rt] = *(const short8*)(A + (size_t)row * APAD + (kc << 5) + (lg << 3));
            else
                aF[rt] = *(const short8*)(A + (size_t)(m0 + row) * 256 + (kc << 5) + (lg << 3));
        }
#pragma unroll
        for (int ct = 0; ct < 4; ++ct)
            bF[ct] = *(const short8*)(Wt + (size_t)kc * CHUNK_E +
                                      (size_t)(cb + (ct << 4) + l16) * 32 + (lg << 3));
#pragma unroll
        for (int rt = 0; rt < 2; ++rt)
#pragma unroll
            for (int ct = 0; ct < 4; ++ct)
                acc[rt][ct] = __builtin_amdgcn_mfma_f32_16x16x32_bf16(
                    aF[rt], bF[ct], acc[rt][ct], 0, 0, 0);
    }

    // cross-half exchange (wave-uniform branch; constant reg indices):
    // red idx 0..15 = row-half 0 partials (dumped by hi), 16..31 = half 1 (by lo)
    if (kh == 0) {
#pragma unroll
        for (int ct = 0; ct < 4; ++ct)
#pragma unroll
            for (int r = 0; r < 4; ++r)
                red[wc][16 | (ct << 2) | r][lane] = acc[1][ct][r];
    } else {
#pragma unroll
        for (int ct = 0; ct < 4; ++ct)
#pragma unroll
            for (int r = 0; r < 4; ++r)
                red[wc][(ct << 2) | r][lane] = acc[0][ct][r];
    }
    __syncthreads();

    // merge own row-half
    float v[4][4];
    if (kh == 0) {
#pragma unroll
        for (int ct = 0; ct < 4; ++ct)
#pragma unroll
            for (int r = 0; r < 4; ++r)
                v[ct][r] = acc[0][ct][r] + red[wc][(ct << 2) | r][lane];
    } else {
#pragma unroll
        for (int ct = 0; ct < 4; ++ct)
#pragma unroll
            for (int r = 0; r < 4; ++r)
                v[ct][r] = acc[1][ct][r] + red[wc][16 | (ct << 2) | r][lane];
    }

    const int rbase = kh << 4;
#pragma unroll
    for (int ct = 0; ct < 4; ++ct)
#pragma unroll
        for (int r = 0; r < 4; ++r) {
            int row = rbase + (lg << 2) + r;
            int col = cb + (ct << 4) + l16;
            float x = v[ct][r];
            if constexpr (GELU) {
                if (bias) x += bias[col];
                x = geluf(x);
            } else {
                if constexpr (RL) x += bf2f(Rl[(size_t)row * APAD + col]);
                else              x += bf2f(Rg[(size_t)(m0 + row) * 256 + col]);
            }
            v[ct][r] = x;
        }

#pragma unroll
    for (int r = 0; r < 4; ++r) {
        float p = 0.f;
#pragma unroll
        for (int ct = 0; ct < 4; ++ct) p += v[ct][r] * v[ct][r];
        p += __shfl_xor(p, 1, 64); p += __shfl_xor(p, 2, 64);
        p += __shfl_xor(p, 4, 64); p += __shfl_xor(p, 8, 64);
        int row = rbase + (lg << 2) + r;
        if (l16 == 0) rowsum[wc][row] = p;     // unique (wc,row) per wave
    }
    __syncthreads();
#pragma unroll
    for (int r = 0; r < 4; ++r) {
        int row = rbase + (lg << 2) + r;
        float tot = rowsum[0][row] + rowsum[1][row] + rowsum[2][row] + rowsum[3][row];
        float rn = rsqrtf(tot * (1.f / 256.f) + 1e-6f);
#pragma unroll
        for (int ct = 0; ct < 4; ++ct) {
            int col = cb + (ct << 4) + l16;
            uint16_t bb = f2bf(v[ct][r] * rn * lnw[col]);
            if constexpr (OG)
                Og[(size_t)(m0 + row) * 256 + col] = bb;
            Ol[(size_t)row * APAD + col] = bb;
        }
    }
    __syncthreads();
}

// ---- W-split dual GEMM: waves 0-3 -> W1, waves 4-7 -> W2, full K, 64 cols ----
// R7 form (compiler-scheduled loads).
// EP2_NONE: each wave group stores its matrix (full-line stores, no barrier).
// EP2_SWIGLU: W1=gate (lo), W2=up (hi); hi dumps to red, lo writes
//   swish(gate)*up -> LDS Ol. Internal barrier; NO trailing barrier.
template<int EPI, bool AL>
DEV void gemm2_ws(int m0, const uint16_t* __restrict__ A,
                  const uint16_t* __restrict__ W1, const uint16_t* __restrict__ W2,
                  uint16_t* __restrict__ O1, uint16_t* __restrict__ O2,
                  uint16_t* __restrict__ Ol, float (&red)[4][32][64])
{
    const int t = threadIdx.x;
    const int w = t >> 6, lane = t & 63, l16 = lane & 15, lg = lane >> 4;
    const int wc = w & 3, cb = wc << 6;
    const uint16_t* W = (w < 4) ? W1 : W2;

    floatx4 acc[2][4];
#pragma unroll
    for (int i = 0; i < 2; ++i)
#pragma unroll
        for (int j = 0; j < 4; ++j) acc[i][j] = (floatx4){0.f, 0.f, 0.f, 0.f};

#pragma unroll
    for (int kc = 0; kc < 8; ++kc) {
        short8 aF[2], bF[4];
#pragma unroll
        for (int rt = 0; rt < 2; ++rt) {
            int row = (rt << 4) + l16;
            if constexpr (AL)
                aF[rt] = *(const short8*)(A + (size_t)row * APAD + (kc << 5) + (lg << 3));
            else
                aF[rt] = *(const short8*)(A + (size_t)(m0 + row) * 256 + (kc << 5) + (lg << 3));
        }
#pragma unroll
        for (int ct = 0; ct < 4; ++ct)
            bF[ct] = *(const short8*)(W + (size_t)kc * CHUNK_E +
                                      (size_t)(cb + (ct << 4) + l16) * 32 + (lg << 3));
#pragma unroll
        for (int rt = 0; rt < 2; ++rt)
#pragma unroll
            for (int ct = 0; ct < 4; ++ct)
                acc[rt][ct] = __builtin_amdgcn_mfma_f32_16x16x32_bf16(
                    aF[rt], bF[ct], acc[rt][ct], 0, 0, 0);
    }

    if constexpr (EPI == EP2_NONE) {
        uint16_t* O = (w < 4) ? O1 : O2;
#pragma unroll
        for (int rt = 0; rt < 2; ++rt)
#pragma unroll
            for (int ct = 0; ct < 4; ++ct)
#pragma unroll
                for (int r = 0; r < 4; ++r) {
                    int row = (rt << 4) + (lg << 2) + r;
                    int col = cb + (ct << 4) + l16;
                    O[(size_t)(m0 + row) * 256 + col] = f2bf(acc[rt][ct][r]);
                }
    } else {  // EP2_SWIGLU
        if (w >= 4) {
#pragma unroll
            for (int rt = 0; rt < 2; ++rt)
#pragma unroll
                for (int ct = 0; ct < 4; ++ct)
#pragma unroll
                    for (int r = 0; r < 4; ++r)
                        red[wc][(rt << 4) | (ct << 2) | r][lane] = acc[rt][ct][r];
        }
        __syncthreads();
        if (w < 4) {
#pragma unroll
            for (int rt = 0; rt < 2; ++rt)
#pragma unroll
                for (int ct = 0; ct < 4; ++ct)
#pragma unroll
                    for (int r = 0; r < 4; ++r) {
                        int row = (rt << 4) + (lg << 2) + r;
                        int col = cb + (ct << 4) + l16;
                        float up = red[wc][(rt << 4) | (ct << 2) | r][lane];
                        Ol[(size_t)row * APAD + col] = f2bf(swishf(acc[rt][ct][r]) * up);
                    }
        }
    }
}

// ---- enc GEMM (K=32): 8-wave x 32-col path, gelu+rms epilogue ----
DEV void gemm_enc(int m0, const uint16_t* __restrict__ A, const uint16_t* __restrict__ Wt,
                  uint16_t* __restrict__ Og, uint16_t* __restrict__ Ol,
                  const float* __restrict__ lnw, float (&rowsum)[8][32])
{
    const int t = threadIdx.x;
    const int w = t >> 6, lane = t & 63, l16 = lane & 15, lg = lane >> 4;

    floatx4 acc[2][2];
#pragma unroll
    for (int i = 0; i < 2; ++i)
#pragma unroll
        for (int j = 0; j < 2; ++j) acc[i][j] = (floatx4){0.f, 0.f, 0.f, 0.f};

    short8 aF[2], bF[2];
#pragma unroll
    for (int rt = 0; rt < 2; ++rt)
        aF[rt] = *(const short8*)(A + (size_t)((rt << 4) + l16) * 40 + (lg << 3));
#pragma unroll
    for (int ct = 0; ct < 2; ++ct)
        bF[ct] = *(const short8*)(Wt + (size_t)((w << 5) + (ct << 4) + l16) * 32 + (lg << 3));
#pragma unroll
    for (int rt = 0; rt < 2; ++rt)
#pragma unroll
        for (int ct = 0; ct < 2; ++ct)
            acc[rt][ct] = __builtin_amdgcn_mfma_f32_16x16x32_bf16(
                aF[rt], bF[ct], acc[rt][ct], 0, 0, 0);

    float v[2][2][4];
#pragma unroll
    for (int rt = 0; rt < 2; ++rt)
#pragma unroll
        for (int ct = 0; ct < 2; ++ct)
#pragma unroll
            for (int r = 0; r < 4; ++r)
                v[rt][ct][r] = geluf(acc[rt][ct][r]);

#pragma unroll
    for (int rt = 0; rt < 2; ++rt)
#pragma unroll
        for (int r = 0; r < 4; ++r) {
            float p = v[rt][0][r] * v[rt][0][r] + v[rt][1][r] * v[rt][1][r];
            p += __shfl_xor(p, 1, 64); p += __shfl_xor(p, 2, 64);
            p += __shfl_xor(p, 4, 64); p += __shfl_xor(p, 8, 64);
            int row = (rt << 4) + (lg << 2) + r;
            if (l16 == 0) rowsum[w][row] = p;
        }
    __syncthreads();
#pragma unroll
    for (int rt = 0; rt < 2; ++rt)
#pragma unroll
        for (int r = 0; r < 4; ++r) {
            int row = (rt << 4) + (lg << 2) + r;
            float tot = rowsum[0][row] + rowsum[1][row] + rowsum[2][row] + rowsum[3][row]
                      + rowsum[4][row] + rowsum[5][row] + rowsum[6][row] + rowsum[7][row];
            float rn = rsqrtf(tot * (1.f / 256.f) + 1e-6f);
#pragma unroll
            for (int ct = 0; ct < 2; ++ct) {
                int col = (w << 5) + (ct << 4) + l16;
                uint16_t bb = f2bf(v[rt][ct][r] * rn * lnw[col]);
                Og[(size_t)(m0 + row) * 256 + col] = bb;
                Ol[(size_t)row * APAD + col] = bb;
            }
        }
    __syncthreads();
}

DEV int rowbase(int blk) { return (blk & 63) * 256 + (blk >> 6) * 32; }

// ---------------- segment kernels (512 blocks x 512 threads) ----------------

__global__ __launch_bounds__(512, 4) void seg0_k(SegArgs sa, const uint16_t* __restrict__ wenc,
                                                 const uint16_t* __restrict__ wq,
                                                 const uint16_t* __restrict__ wk,
                                                 const uint16_t* __restrict__ wv,
                                                 const uint16_t* __restrict__ wg)
{
    __shared__ float rowsum[8][32];
    __shared__ float red[4][32][64];
    __shared__ __align__(16) uint16_t actS[32][40];
    __shared__ __align__(16) uint16_t T0[32][APAD];
    const int t = threadIdx.x;
    const int m0 = rowbase(blockIdx.x);
    if (t < 256) {
        int r = t >> 3, c = (t & 7) << 2;
        float4 f = *(const float4*)(sa.action + (size_t)(m0 + r) * 32 + c);
        uint16_t tmp[4] = { f2bf(f.x), f2bf(f.y), f2bf(f.z), f2bf(f.w) };
        *(uint2*)&actS[r][c] = *(uint2*)tmp;
    }
    {
        const float4* ob = (const float4*)sa.obs + (size_t)m0 * 64;
        uint2* od = (uint2*)sa.obsb + (size_t)m0 * 64;
#pragma unroll
        for (int j = 0; j < 4; ++j) {
            float4 f = ob[(j << 9) + t];
            uint16_t tmp[4] = { f2bf(f.x), f2bf(f.y), f2bf(f.z), f2bf(f.w) };
            od[(j << 9) + t] = *(uint2*)tmp;
        }
    }
    __syncthreads();
    // x = rms(gelu(action@wenc)) -> LDS T0 + global xb (g1's ln1 residual)
    gemm_enc(m0, &actS[0][0], wenc, sa.xb, &T0[0][0], sa.ln0, rowsum);
    gemm2_ws<EP2_NONE, true>(m0, &T0[0][0], wq, wk, sa.bq, sa.bk, nullptr, red);
    gemm2_ws<EP2_NONE, true>(m0, &T0[0][0], wv, wg, sa.bv, sa.bg, nullptr, red);
}

__global__ __launch_bounds__(512, 4) void attn_k(SegArgs sa, const float* __restrict__ gns,
                                                 const float* __restrict__ gnb)
{
    __shared__ __align__(16) uint16_t QS[256][40];
    __shared__ __align__(16) uint16_t Ks[256][40];
    __shared__ __align__(16) uint16_t Vt[32][264];
    const int b = blockIdx.x & 63, h = blockIdx.x >> 6;
    const float l2g = sa.l2g[h];
    const int t = threadIdx.x, w = t >> 6, lane = t & 63, l16 = lane & 15, lg = lane >> 4;
    const size_t base = ((size_t)b * 256) * 256 + (size_t)h * 32;
    const uint16_t *q = sa.bq, *kbuf = sa.bk, *vbuf = sa.bv, *g = sa.bg;
    uint16_t* out = sa.brg;

    if (t < 256) {
        const uint4* qr = (const uint4*)(q + base + (size_t)t * 256);
        *(uint4*)&QS[t][0] = qr[0]; *(uint4*)&QS[t][8] = qr[1];
        *(uint4*)&QS[t][16] = qr[2]; *(uint4*)&QS[t][24] = qr[3];
        const uint4* kr = (const uint4*)(kbuf + base + (size_t)t * 256);
        *(uint4*)&Ks[t][0] = kr[0]; *(uint4*)&Ks[t][8] = kr[1];
        *(uint4*)&Ks[t][16] = kr[2]; *(uint4*)&Ks[t][24] = kr[3];
    } else {
        int c = t - 256;
        union { uint4 v4[4]; uint16_t u[32]; } vv;
        const uint4* vr = (const uint4*)(vbuf + base + (size_t)c * 256);
        vv.v4[0] = vr[0]; vv.v4[1] = vr[1]; vv.v4[2] = vr[2]; vv.v4[3] = vr[3];
#pragma unroll
        for (int d = 0; d < 32; ++d) Vt[d][c] = vv.u[d];
    }
    __syncthreads();

    // balanced strips: wave w owns 16-row half-strips {w, 15-w} (work sums to 9)
    const int iA = w, iB = 15 - w;
    short8 qFA = *(const short8*)&QS[(iA << 4) + l16][lg << 3];
    short8 qFB = *(const short8*)&QS[(iB << 4) + l16][lg << 3];

    const float invsq = 0.17677669529663687f;

    floatx4 raccA[2], raccB[2];
    raccA[0] = (floatx4){0,0,0,0}; raccA[1] = (floatx4){0,0,0,0};
    raccB[0] = (floatx4){0,0,0,0}; raccB[1] = (floatx4){0,0,0,0};

    auto do_strip = [&](int si, short8 qF, floatx4 (&racc)[2]) {
        const int jtmax = ((si << 4) + 15) >> 5;
        for (int jt = 0; jt <= jtmax; ++jt) {
            const int j0 = jt << 5;
            floatx4 sacc[2];
            sacc[0] = (floatx4){0,0,0,0}; sacc[1] = (floatx4){0,0,0,0};
            short8 kF[2];
#pragma unroll
            for (int ct = 0; ct < 2; ++ct)
                kF[ct] = *(const short8*)&Ks[j0 + (ct << 4) + l16][lg << 3];
#pragma unroll
            for (int ct = 0; ct < 2; ++ct)
                sacc[ct] = __builtin_amdgcn_mfma_f32_16x16x32_bf16(
                    qF, kF[ct], sacc[ct], 0, 0, 0);
#pragma unroll
            for (int ct = 0; ct < 2; ++ct)
#pragma unroll
                for (int r = 0; r < 4; ++r) {
                    int row16 = (lg << 2) + r;
                    int i = (si << 4) + row16;
                    int j = j0 + (ct << 4) + l16;
                    float svv = 0.f;
                    if (i >= j)
                        svv = sacc[ct][r] * invsq *
                              exp2f((float)((i >> 3) - (j >> 3)) * l2g);
                    QS[(si << 4) + row16][(ct << 4) + l16] = f2bf(svv);
                }
            short8 vF[2];
#pragma unroll
            for (int ct = 0; ct < 2; ++ct)
                vF[ct] = *(const short8*)&Vt[(ct << 4) + l16][j0 + (lg << 3)];
            short8 sF = *(const short8*)&QS[(si << 4) + l16][lg << 3];
#pragma unroll
            for (int ct = 0; ct < 2; ++ct)
                racc[ct] = __builtin_amdgcn_mfma_f32_16x16x32_bf16(
                    sF, vF[ct], racc[ct], 0, 0, 0);
        }
    };
    do_strip(iA, qFA, raccA);
    do_strip(iB, qFB, raccB);

    auto epi = [&](int si, floatx4 (&racc)[2]) {
#pragma unroll
        for (int r = 0; r < 4; ++r) {
            float v0 = racc[0][r], v1 = racc[1][r];
            float s1 = v0 + v1, s2 = v0 * v0 + v1 * v1;
            s1 += __shfl_xor(s1, 1, 64); s2 += __shfl_xor(s2, 1, 64);
            s1 += __shfl_xor(s1, 2, 64); s2 += __shfl_xor(s2, 2, 64);
            s1 += __shfl_xor(s1, 4, 64); s2 += __shfl_xor(s2, 4, 64);
            s1 += __shfl_xor(s1, 8, 64); s2 += __shfl_xor(s2, 8, 64);
            float mu = s1 * (1.f / 32.f);
            float var = s2 * (1.f / 32.f) - mu * mu;
            float rstd = rsqrtf(var + 1e-5f);
            int srow = (si << 4) + (lg << 2) + r;
            size_t obase = ((size_t)b * 256 + srow) * 256 + (size_t)h * 32;
#pragma unroll
            for (int ct = 0; ct < 2; ++ct) {
                int d = (ct << 4) + l16;
                float x = ct ? v1 : v0;
                float y = (x - mu) * rstd * gns[h * 32 + d] + gnb[h * 32 + d];
                float gv = swishf(bf2f(g[obase + d]));
                out[obase + d] = f2bf(y * gv);
            }
        }
    };
    epi(iA, raccA);
    epi(iB, raccB);
}

__global__ __launch_bounds__(512, 4) void g1_k(SegArgs sa,
    const uint16_t* __restrict__ wo, const float* __restrict__ ln1,
    const uint16_t* __restrict__ wq, const uint16_t* __restrict__ wk,
    const uint16_t* __restrict__ wv, const uint16_t* __restrict__ wg)
{
    __shared__ float rowsum[8][32];
    __shared__ float red[4][32][64];
    __shared__ __align__(16) uint16_t T0[32][APAD];
    __shared__ __align__(16) uint16_t T1[32][APAD];
    const int m0 = rowbase(blockIdx.x);
    stage32(sa.brg, m0, &T1[0][0]);
    __syncthreads();
    // x1 = rms(x + brg@wo) -> LDS T0 (consumed only by wk/wv)
    gemm_ks<true, false, false, false>(m0, &T1[0][0], wo,
        nullptr, &T0[0][0], nullptr, sa.xb, nullptr, ln1, rowsum, red);
    // T1 free (its reads finished before gemm_ks's exchange barrier): stage obsb
    stage32(sa.obsb, m0, &T1[0][0]);
    gemm2_ws<EP2_NONE, true>(m0, &T0[0][0], wk, wv, sa.bk, sa.bv, nullptr, red);
    __syncthreads();
    gemm2_ws<EP2_NONE, true>(m0, &T1[0][0], wq, wg, sa.bq, sa.bg, nullptr, red);
}

__global__ __launch_bounds__(512, 4) void g2_k(SegArgs sa,
    const uint16_t* __restrict__ wo, const float* __restrict__ ln2,
    const uint16_t* __restrict__ wswg, const uint16_t* __restrict__ wsw1,
    const uint16_t* __restrict__ wsw2, const float* __restrict__ ln3,
    const uint16_t* __restrict__ nwq, const uint16_t* __restrict__ nwk,
    const uint16_t* __restrict__ nwv, const uint16_t* __restrict__ nwg)
{
    __shared__ float rowsum[8][32];
    __shared__ float red[4][32][64];
    __shared__ __align__(16) uint16_t T0[32][APAD];
    __shared__ __align__(16) uint16_t T1[32][APAD];
    const int m0 = rowbase(blockIdx.x);
    stage32(sa.brg, m0, &T1[0][0]);
    __syncthreads();
    // x2 = rms(obs + brg@wo) -> LDS T0
    gemm_ks<true, false, false, false>(m0, &T1[0][0], wo,
        nullptr, &T0[0][0], nullptr, sa.obsb, nullptr, ln2, rowsum, red);
    // swiglu gate*up -> LDS T1 (gate=lo/swg, up=hi/sw1 via red); no trailing barrier
    gemm2_ws<EP2_SWIGLU, true>(m0, &T0[0][0], wswg, wsw1, nullptr, nullptr, &T1[0][0], red);
    __syncthreads();   // T1 visible to all waves
    // x3 = rms(x2 + T1@sw2): T0 in-place (resid rows read by the owning wave
    // pre-rowsum-barrier, rewritten post-barrier by the same thread).
    // Global xb copy for next g1 / head.
    gemm_ks<true, true, true, false>(m0, &T1[0][0], wsw2,
        sa.xb, &T0[0][0], nullptr, nullptr, &T0[0][0], ln3, rowsum, red);
    if (nwq) {
        gemm2_ws<EP2_NONE, true>(m0, &T0[0][0], nwq, nwk, sa.bq, sa.bk, nullptr, red);
        gemm2_ws<EP2_NONE, true>(m0, &T0[0][0], nwv, nwg, sa.bv, sa.bg, nullptr, red);
    }
}

__global__ __launch_bounds__(512, 4) void head_k(SegArgs sa, const uint16_t* __restrict__ hw1t)
{
    __shared__ float rowsum[8][32];
    __shared__ float red[4][32][64];   // reused as w2s after the GEMM
    __shared__ __align__(16) uint16_t T0[32][APAD];
    const int t = threadIdx.x;
    const int m0 = rowbase(blockIdx.x);
    // h = rms(gelu(x@hw1+hb1)) -> LDS T0 (A = xb global)
    gemm_ks<false, false, false, true>(m0, sa.xb, hw1t,
        nullptr, &T0[0][0], sa.hb1, nullptr, nullptr, sa.hln, rowsum, red);
    float* w2s = &red[0][0][0];        // red dead after gemm_ks's final barrier
#pragma unroll
    for (int j = 0; j < 16; ++j) w2s[(j << 9) + t] = sa.hw2[(j << 9) + t];
    __syncthreads();
    {
        int n = t & 31, rs = t >> 5;    // rs 0..15
#pragma unroll
        for (int rr = 0; rr < 2; ++rr) {
            int lrow = (rr << 4) + rs;
            float a0 = sa.hb2[n];
#pragma unroll 8
            for (int kk = 0; kk < 256; ++kk)
                a0 += bf2f(T0[lrow][kk]) * w2s[kk * 32 + n];
            sa.outp[(size_t)(m0 + lrow) * 32 + n] = a0;
        }
    }
}

// ---------------- host ----------------
extern "C" void kernel_launch(void* const* d_in, const int* in_sizes, int n_in,
                              void* d_out, int out_size, void* d_ws, size_t ws_size,
                              hipStream_t stream)
{
    const float* action = (const float*)d_in[0];
    const float* obs    = (const float*)d_in[1];
    const float* w_enc  = (const float*)d_in[2];
    const float* ln0    = (const float*)d_in[3];
    const float* wq1 = (const float*)d_in[4];
    const float* wk1 = (const float*)d_in[5];
    const float* wv1 = (const float*)d_in[6];
    const float* wg1 = (const float*)d_in[7];
    const float* wo1 = (const float*)d_in[8];
    const float* gns1 = (const float*)d_in[9];
    const float* gnb1 = (const float*)d_in[10];
    const float* ln1  = (const float*)d_in[11];
    const float* wq2 = (const float*)d_in[12];
    const float* wk2 = (const float*)d_in[13];
    const float* wv2 = (const float*)d_in[14];
    const float* wg2 = (const float*)d_in[15];
    const float* wo2 = (const float*)d_in[16];
    const float* gns2 = (const float*)d_in[17];
    const float* gnb2 = (const float*)d_in[18];
    const float* ln2  = (const float*)d_in[19];
    const float* swgp = (const float*)d_in[20];
    const float* sw1p = (const float*)d_in[21];
    const float* sw2p = (const float*)d_in[22];
    const float* ln3  = (const float*)d_in[23];
    const float* hw1  = (const float*)d_in[24];
    const float* hb1  = (const float*)d_in[25];
    const float* hln  = (const float*)d_in[26];
    const float* hw2  = (const float*)d_in[27];
    const float* hb2  = (const float*)d_in[28];

    char* ws = (char*)d_ws;
    uint16_t* wt   = (uint16_t*)(ws + 0);
    uint16_t* actb = (uint16_t*)(ws + 6291456);
    uint16_t* obsb = (uint16_t*)(ws + 7340032);
    uint16_t* xb   = (uint16_t*)(ws + 15728640);
    uint16_t* bq   = (uint16_t*)(ws + 24117248);
    uint16_t* bk   = (uint16_t*)(ws + 32505856);
    uint16_t* bv   = (uint16_t*)(ws + 40894464);
    uint16_t* bg   = (uint16_t*)(ws + 49283072);
    uint16_t* brg  = (uint16_t*)(ws + 57671680);

    uint16_t* wtenc = wt;
    uint16_t* hw1t  = wt + CHUNK_E + (size_t)39 * MAT_E;
    auto WTp = [&](int ti, int s) { return wt + CHUNK_E + (size_t)(ti * 3 + s) * MAT_E; };

    TArg ta;
    ta.src[0] = w_enc;
    ta.src[1] = wq1;  ta.src[2] = wk1;  ta.src[3] = wv1;  ta.src[4] = wg1;  ta.src[5] = wo1;
    ta.src[6] = wq2;  ta.src[7] = wk2;  ta.src[8] = wv2;  ta.src[9] = wg2;  ta.src[10] = wo2;
    ta.src[11] = swgp; ta.src[12] = sw1p; ta.src[13] = sw2p; ta.src[14] = hw1;
    tpose_k<<<dim3(4, 8, 41), 256, 0, stream>>>(ta, wt);

    SegArgs sa;
    sa.action = action; sa.obs = obs;
    sa.actb = actb; sa.obsb = obsb; sa.xb = xb;
    sa.bq = bq; sa.bk = bk; sa.bv = bv; sa.bg = bg; sa.brg = brg;
    sa.ln0 = ln0; sa.hb1 = hb1; sa.hln = hln; sa.hw2 = hw2; sa.hb2 = hb2;
    sa.outp = (float*)d_out;
    {
        const double a = log(1.0 / 32.0), bb = log(1.0 / 512.0);
        for (int hh = 0; hh < 8; ++hh) {
            double lg = a + (bb - a) * hh / 7.0;
            double gam = 1.0 - exp(lg);
            sa.l2g[hh] = (float)(log(gam) / log(2.0));
        }
    }

    dim3 GB(512), TB(512);
    seg0_k<<<GB, TB, 0, stream>>>(sa, wtenc, WTp(0, 0), WTp(1, 0), WTp(2, 0), WTp(3, 0));
    for (int b3 = 0; b3 < 3; ++b3) {
        attn_k<<<GB, TB, 0, stream>>>(sa, gns1 + b3 * 256, gnb1 + b3 * 256);
        g1_k<<<GB, TB, 0, stream>>>(sa, WTp(4, b3), ln1 + b3 * 256,
                                    WTp(5, b3), WTp(6, b3), WTp(7, b3), WTp(8, b3));
        attn_k<<<GB, TB, 0, stream>>>(sa, gns2 + b3 * 256, gnb2 + b3 * 256);
        g2_k<<<GB, TB, 0, stream>>>(sa, WTp(9, b3), ln2 + b3 * 256,
                                    WTp(10, b3), WTp(11, b3), WTp(12, b3), ln3 + b3 * 256,
                                    b3 < 2 ? WTp(0, b3 + 1) : nullptr,
                                    b3 < 2 ? WTp(1, b3 + 1) : nullptr,
                                    b3 < 2 ? WTp(2, b3 + 1) : nullptr,
                                    b3 < 2 ? WTp(3, b3 + 1) : nullptr);
    }
    head_k<<<GB, TB, 0, stream>>>(sa, hw1t);
}

// Round 10
// 493.229 us; speedup vs baseline: 1.0282x; 1.0123x over previous
//
#include <hip/hip_runtime.h>
#include <cstdint>
#include <cmath>

typedef __attribute__((ext_vector_type(8))) short short8;
typedef __attribute__((ext_vector_type(4))) float floatx4;

#define DEV static __device__ __forceinline__

DEV float bf2f(uint16_t u) {
    union { uint32_t i; float f; } v; v.i = ((uint32_t)u) << 16; return v.f;
}
DEV uint16_t f2bf(float f) {
    union { float f; uint32_t i; } v; v.f = f;
    uint32_t r = (v.i + 0x7FFFu + ((v.i >> 16) & 1u)) >> 16;
    return (uint16_t)r;
}
DEV float swishf(float x) { return x / (1.f + __expf(-x)); }
DEV float geluf(float x) {
    const float c = 0.7978845608028654f;
    float t = tanhf(c * (x + 0.044715f * x * x * x));
    return 0.5f * x * (1.f + t);
}

#define CHUNK_E 8192
#define MAT_E   65536
#define APAD    264

// ---- Geometry (GEMM kernels): 512 blocks x 512 threads, 32-row tiles ----
// R7/R9 structure + R10 delta: DEPTH-3 ROLLING B-PRELOAD in both GEMM
// inner loops. bF[3][4] slots, preload kc 0..2, refill kc+3 right after the
// MFMAs that consume a slot -> ~8 loads in flight per wave (was ~3-4 at the
// compiler's VGPR=64 schedule). 12 live fragments = 48 VGPR; total ~105-110,
// under the (512,4) cap of 128 (R8's 16-deep preload spilled at 64 frags).
// 512 blocks -> 2 blocks/CU -> 16 waves/CU. Block: batch b = blk & 63 -> XCD b%8.

// ---- transpose+convert: W[K,N=256] fp32 -> packed chunks [kc][n][32] bf16 ----
struct TArg { const float* src[15]; };

__global__ __launch_bounds__(256) void tpose_k(TArg ta, uint16_t* __restrict__ arena) {
    int z = blockIdx.z;
    const float* src; uint16_t* dst;
    if (z == 0) {
        if (blockIdx.y) return;
        src = ta.src[0]; dst = arena;                            // w_enc [32,256]
    } else if (z <= 39) {
        int q = z - 1; int ti = q / 3, s = q % 3;
        src = ta.src[1 + ti] + (size_t)s * 65536;
        dst = arena + CHUNK_E + (size_t)(ti * 3 + s) * MAT_E;
    } else {
        src = ta.src[14]; dst = arena + CHUNK_E + (size_t)39 * MAT_E;   // hw1
    }
    int k0 = blockIdx.y << 5;
    int n0 = blockIdx.x << 6;
    __shared__ __align__(16) uint16_t tile[32][72];
    int t = threadIdx.x;
    {
        int r = t >> 3, c = (t & 7) << 3;
        const float* s0 = src + (size_t)(k0 + r) * 256 + n0 + c;
        float4 f0 = *(const float4*)s0;
        float4 f1 = *(const float4*)(s0 + 4);
        tile[r][c + 0] = f2bf(f0.x); tile[r][c + 1] = f2bf(f0.y);
        tile[r][c + 2] = f2bf(f0.z); tile[r][c + 3] = f2bf(f0.w);
        tile[r][c + 4] = f2bf(f1.x); tile[r][c + 5] = f2bf(f1.y);
        tile[r][c + 6] = f2bf(f1.z); tile[r][c + 7] = f2bf(f1.w);
    }
    __syncthreads();
    {
        int n = t >> 2, c = (t & 3) << 3;
        uint16_t tmp[8];
#pragma unroll
        for (int j = 0; j < 8; ++j) tmp[j] = tile[c + j][n];
        *(uint4*)&dst[(size_t)(k0 >> 5) * CHUNK_E + (size_t)(n0 + n) * 32 + c] = *(uint4*)tmp;
    }
}

// ---------------- shared pieces ----------------
struct SegArgs {
    const float* action; const float* obs;
    uint16_t *actb, *obsb, *xb, *bq, *bk, *bv, *bg, *brg;
    const float *ln0, *hb1, *hln, *hw2, *hb2;
    float* outp;
    float l2g[8];
};

enum { EP2_NONE = 0, EP2_SWIGLU = 1 };

// stage a 32x256 bf16 tile (global, row stride 256) into LDS [32][APAD]
DEV void stage32(const uint16_t* __restrict__ g, int m0, uint16_t* __restrict__ lds) {
    const int t = threadIdx.x;
#pragma unroll
    for (int j = 0; j < 2; ++j) {
        int u = t + (j << 9);             // 1024 short8 units
        int r = u >> 5, cc = (u & 31) << 3;
        *(short8*)(lds + (size_t)r * APAD + cc) =
            *(const short8*)(g + (size_t)(m0 + r) * 256 + cc);
    }
}

// ---- split-K single GEMM: 32x256 tile, K=256, RMS-family epilogue ----
// Wave (wc=w&3, kh=w>>2): cols [wc*64,+64), K-half kh. Depth-3 rolling B
// preload (bF[3][4], ~8 loads in flight). Epilogue: wave keeps row-half kh,
// dumps the other to red; all 8 waves merge+rms+store 16 rows each.
// AL: A in LDS [32][APAD] else global stride 256 rows m0+...
// OG: also store to global Og. Ol (LDS [32][APAD]) always written.
// GELU: gelu(+bias); else residual (RL: LDS Rl else global Rg) add.
// Ends with __syncthreads() -> Ol immediately consumable.
template<bool AL, bool OG, bool RL, bool GELU>
DEV void gemm_ks(int m0, const uint16_t* __restrict__ A, const uint16_t* __restrict__ Wt,
                 uint16_t* __restrict__ Og, uint16_t* __restrict__ Ol,
                 const float* __restrict__ bias,
                 const uint16_t* __restrict__ Rg, const uint16_t* __restrict__ Rl,
                 const float* __restrict__ lnw,
                 float (&rowsum)[8][32], float (&red)[4][32][64])
{
    const int t = threadIdx.x;
    const int w = t >> 6, lane = t & 63, l16 = lane & 15, lg = lane >> 4;
    const int wc = w & 3, cb = wc << 6;
    const int kh = w >> 2;
    const int kbase = kh << 2;

    floatx4 acc[2][4];
#pragma unroll
    for (int i = 0; i < 2; ++i)
#pragma unroll
        for (int j = 0; j < 4; ++j) acc[i][j] = (floatx4){0.f, 0.f, 0.f, 0.f};

    // depth-3 rolling B preload
    short8 bF[3][4];
#pragma unroll
    for (int s = 0; s < 3; ++s)
#pragma unroll
        for (int ct = 0; ct < 4; ++ct)
            bF[s][ct] = *(const short8*)(Wt + (size_t)(kbase + s) * CHUNK_E +
                                         (size_t)(cb + (ct << 4) + l16) * 32 + (lg << 3));

#pragma unroll
    for (int k2 = 0; k2 < 4; ++k2) {
        const int kc = kbase + k2;
        const int slot = k2 % 3;
        short8 aF[2];
#pragma unroll
        for (int rt = 0; rt < 2; ++rt) {
            int row = (rt << 4) + l16;
            if constexpr (AL)
                aF[rt] = *(const short8*)(A + (size_t)row * APAD + (kc << 5) + (lg << 3));
            else
                aF[rt] = *(const short8*)(A + (size_t)(m0 + row) * 256 + (kc << 5) + (lg << 3));
        }
#pragma unroll
        for (int rt = 0; rt < 2; ++rt)
#pragma unroll
            for (int ct = 0; ct < 4; ++ct)
                acc[rt][ct] = __builtin_amdgcn_mfma_f32_16x16x32_bf16(
                    aF[rt], bF[slot][ct], acc[rt][ct], 0, 0, 0);
        if (k2 + 3 < 4) {
#pragma unroll
            for (int ct = 0; ct < 4; ++ct)
                bF[slot][ct] = *(const short8*)(Wt + (size_t)(kbase + k2 + 3) * CHUNK_E +
                                                (size_t)(cb + (ct << 4) + l16) * 32 + (lg << 3));
        }
    }

    // cross-half exchange (wave-uniform branch; constant reg indices):
    // red idx 0..15 = row-half 0 partials (dumped by hi), 16..31 = half 1 (by lo)
    if (kh == 0) {
#pragma unroll
        for (int ct = 0; ct < 4; ++ct)
#pragma unroll
            for (int r = 0; r < 4; ++r)
                red[wc][16 | (ct << 2) | r][lane] = acc[1][ct][r];
    } else {
#pragma unroll
        for (int ct = 0; ct < 4; ++ct)
#pragma unroll
            for (int r = 0; r < 4; ++r)
                red[wc][(ct << 2) | r][lane] = acc[0][ct][r];
    }
    __syncthreads();

    // merge own row-half
    float v[4][4];
    if (kh == 0) {
#pragma unroll
        for (int ct = 0; ct < 4; ++ct)
#pragma unroll
            for (int r = 0; r < 4; ++r)
                v[ct][r] = acc[0][ct][r] + red[wc][(ct << 2) | r][lane];
    } else {
#pragma unroll
        for (int ct = 0; ct < 4; ++ct)
#pragma unroll
            for (int r = 0; r < 4; ++r)
                v[ct][r] = acc[1][ct][r] + red[wc][16 | (ct << 2) | r][lane];
    }

    const int rbase = kh << 4;
#pragma unroll
    for (int ct = 0; ct < 4; ++ct)
#pragma unroll
        for (int r = 0; r < 4; ++r) {
            int row = rbase + (lg << 2) + r;
            int col = cb + (ct << 4) + l16;
            float x = v[ct][r];
            if constexpr (GELU) {
                if (bias) x += bias[col];
                x = geluf(x);
            } else {
                if constexpr (RL) x += bf2f(Rl[(size_t)row * APAD + col]);
                else              x += bf2f(Rg[(size_t)(m0 + row) * 256 + col]);
            }
            v[ct][r] = x;
        }

#pragma unroll
    for (int r = 0; r < 4; ++r) {
        float p = 0.f;
#pragma unroll
        for (int ct = 0; ct < 4; ++ct) p += v[ct][r] * v[ct][r];
        p += __shfl_xor(p, 1, 64); p += __shfl_xor(p, 2, 64);
        p += __shfl_xor(p, 4, 64); p += __shfl_xor(p, 8, 64);
        int row = rbase + (lg << 2) + r;
        if (l16 == 0) rowsum[wc][row] = p;     // unique (wc,row) per wave
    }
    __syncthreads();
#pragma unroll
    for (int r = 0; r < 4; ++r) {
        int row = rbase + (lg << 2) + r;
        float tot = rowsum[0][row] + rowsum[1][row] + rowsum[2][row] + rowsum[3][row];
        float rn = rsqrtf(tot * (1.f / 256.f) + 1e-6f);
#pragma unroll
        for (int ct = 0; ct < 4; ++ct) {
            int col = cb + (ct << 4) + l16;
            uint16_t bb = f2bf(v[ct][r] * rn * lnw[col]);
            if constexpr (OG)
                Og[(size_t)(m0 + row) * 256 + col] = bb;
            Ol[(size_t)row * APAD + col] = bb;
        }
    }
    __syncthreads();
}

// ---- W-split dual GEMM: waves 0-3 -> W1, waves 4-7 -> W2, full K, 64 cols ----
// Depth-3 rolling B preload (bF[3][4]; refill kc+3 after consuming a slot).
// EP2_NONE: each wave group stores its matrix (full-line stores, no barrier).
// EP2_SWIGLU: W1=gate (lo), W2=up (hi); hi dumps to red, lo writes
//   swish(gate)*up -> LDS Ol. Internal barrier; NO trailing barrier.
template<int EPI, bool AL>
DEV void gemm2_ws(int m0, const uint16_t* __restrict__ A,
                  const uint16_t* __restrict__ W1, const uint16_t* __restrict__ W2,
                  uint16_t* __restrict__ O1, uint16_t* __restrict__ O2,
                  uint16_t* __restrict__ Ol, float (&red)[4][32][64])
{
    const int t = threadIdx.x;
    const int w = t >> 6, lane = t & 63, l16 = lane & 15, lg = lane >> 4;
    const int wc = w & 3, cb = wc << 6;
    const uint16_t* W = (w < 4) ? W1 : W2;
    const size_t wcol = (size_t)(cb + l16) * 32 + (lg << 3);

    floatx4 acc[2][4];
#pragma unroll
    for (int i = 0; i < 2; ++i)
#pragma unroll
        for (int j = 0; j < 4; ++j) acc[i][j] = (floatx4){0.f, 0.f, 0.f, 0.f};

    // depth-3 rolling B preload
    short8 bF[3][4];
#pragma unroll
    for (int s = 0; s < 3; ++s)
#pragma unroll
        for (int ct = 0; ct < 4; ++ct)
            bF[s][ct] = *(const short8*)(W + (size_t)s * CHUNK_E + wcol +
                                         (size_t)(ct << 4) * 32);

#pragma unroll
    for (int kc = 0; kc < 8; ++kc) {
        const int slot = kc % 3;
        short8 aF[2];
#pragma unroll
        for (int rt = 0; rt < 2; ++rt) {
            int row = (rt << 4) + l16;
            if constexpr (AL)
                aF[rt] = *(const short8*)(A + (size_t)row * APAD + (kc << 5) + (lg << 3));
            else
                aF[rt] = *(const short8*)(A + (size_t)(m0 + row) * 256 + (kc << 5) + (lg << 3));
        }
#pragma unroll
        for (int rt = 0; rt < 2; ++rt)
#pragma unroll
            for (int ct = 0; ct < 4; ++ct)
                acc[rt][ct] = __builtin_amdgcn_mfma_f32_16x16x32_bf16(
                    aF[rt], bF[slot][ct], acc[rt][ct], 0, 0, 0);
        if (kc + 3 < 8) {
#pragma unroll
            for (int ct = 0; ct < 4; ++ct)
                bF[slot][ct] = *(const short8*)(W + (size_t)(kc + 3) * CHUNK_E + wcol +
                                                (size_t)(ct << 4) * 32);
        }
    }

    if constexpr (EPI == EP2_NONE) {
        uint16_t* O = (w < 4) ? O1 : O2;
#pragma unroll
        for (int rt = 0; rt < 2; ++rt)
#pragma unroll
            for (int ct = 0; ct < 4; ++ct)
#pragma unroll
                for (int r = 0; r < 4; ++r) {
                    int row = (rt << 4) + (lg << 2) + r;
                    int col = cb + (ct << 4) + l16;
                    O[(size_t)(m0 + row) * 256 + col] = f2bf(acc[rt][ct][r]);
                }
    } else {  // EP2_SWIGLU
        if (w >= 4) {
#pragma unroll
            for (int rt = 0; rt < 2; ++rt)
#pragma unroll
                for (int ct = 0; ct < 4; ++ct)
#pragma unroll
                    for (int r = 0; r < 4; ++r)
                        red[wc][(rt << 4) | (ct << 2) | r][lane] = acc[rt][ct][r];
        }
        __syncthreads();
        if (w < 4) {
#pragma unroll
            for (int rt = 0; rt < 2; ++rt)
#pragma unroll
                for (int ct = 0; ct < 4; ++ct)
#pragma unroll
                    for (int r = 0; r < 4; ++r) {
                        int row = (rt << 4) + (lg << 2) + r;
                        int col = cb + (ct << 4) + l16;
                        float up = red[wc][(rt << 4) | (ct << 2) | r][lane];
                        Ol[(size_t)row * APAD + col] = f2bf(swishf(acc[rt][ct][r]) * up);
                    }
        }
    }
}

// ---- enc GEMM (K=32): 8-wave x 32-col path, gelu+rms epilogue ----
DEV void gemm_enc(int m0, const uint16_t* __restrict__ A, const uint16_t* __restrict__ Wt,
                  uint16_t* __restrict__ Og, uint16_t* __restrict__ Ol,
                  const float* __restrict__ lnw, float (&rowsum)[8][32])
{
    const int t = threadIdx.x;
    const int w = t >> 6, lane = t & 63, l16 = lane & 15, lg = lane >> 4;

    floatx4 acc[2][2];
#pragma unroll
    for (int i = 0; i < 2; ++i)
#pragma unroll
        for (int j = 0; j < 2; ++j) acc[i][j] = (floatx4){0.f, 0.f, 0.f, 0.f};

    short8 aF[2], bF[2];
#pragma unroll
    for (int rt = 0; rt < 2; ++rt)
        aF[rt] = *(const short8*)(A + (size_t)((rt << 4) + l16) * 40 + (lg << 3));
#pragma unroll
    for (int ct = 0; ct < 2; ++ct)
        bF[ct] = *(const short8*)(Wt + (size_t)((w << 5) + (ct << 4) + l16) * 32 + (lg << 3));
#pragma unroll
    for (int rt = 0; rt < 2; ++rt)
#pragma unroll
        for (int ct = 0; ct < 2; ++ct)
            acc[rt][ct] = __builtin_amdgcn_mfma_f32_16x16x32_bf16(
                aF[rt], bF[ct], acc[rt][ct], 0, 0, 0);

    float v[2][2][4];
#pragma unroll
    for (int rt = 0; rt < 2; ++rt)
#pragma unroll
        for (int ct = 0; ct < 2; ++ct)
#pragma unroll
            for (int r = 0; r < 4; ++r)
                v[rt][ct][r] = geluf(acc[rt][ct][r]);

#pragma unroll
    for (int rt = 0; rt < 2; ++rt)
#pragma unroll
        for (int r = 0; r < 4; ++r) {
            float p = v[rt][0][r] * v[rt][0][r] + v[rt][1][r] * v[rt][1][r];
            p += __shfl_xor(p, 1, 64); p += __shfl_xor(p, 2, 64);
            p += __shfl_xor(p, 4, 64); p += __shfl_xor(p, 8, 64);
            int row = (rt << 4) + (lg << 2) + r;
            if (l16 == 0) rowsum[w][row] = p;
        }
    __syncthreads();
#pragma unroll
    for (int rt = 0; rt < 2; ++rt)
#pragma unroll
        for (int r = 0; r < 4; ++r) {
            int row = (rt << 4) + (lg << 2) + r;
            float tot = rowsum[0][row] + rowsum[1][row] + rowsum[2][row] + rowsum[3][row]
                      + rowsum[4][row] + rowsum[5][row] + rowsum[6][row] + rowsum[7][row];
            float rn = rsqrtf(tot * (1.f / 256.f) + 1e-6f);
#pragma unroll
            for (int ct = 0; ct < 2; ++ct) {
                int col = (w << 5) + (ct << 4) + l16;
                uint16_t bb = f2bf(v[rt][ct][r] * rn * lnw[col]);
                Og[(size_t)(m0 + row) * 256 + col] = bb;
                Ol[(size_t)row * APAD + col] = bb;
            }
        }
    __syncthreads();
}

DEV int rowbase(int blk) { return (blk & 63) * 256 + (blk >> 6) * 32; }

// ---------------- segment kernels (512 blocks x 512 threads) ----------------

__global__ __launch_bounds__(512, 4) void seg0_k(SegArgs sa, const uint16_t* __restrict__ wenc,
                                                 const uint16_t* __restrict__ wq,
                                                 const uint16_t* __restrict__ wk,
                                                 const uint16_t* __restrict__ wv,
                                                 const uint16_t* __restrict__ wg)
{
    __shared__ float rowsum[8][32];
    __shared__ float red[4][32][64];
    __shared__ __align__(16) uint16_t actS[32][40];
    __shared__ __align__(16) uint16_t T0[32][APAD];
    const int t = threadIdx.x;
    const int m0 = rowbase(blockIdx.x);
    if (t < 256) {
        int r = t >> 3, c = (t & 7) << 2;
        float4 f = *(const float4*)(sa.action + (size_t)(m0 + r) * 32 + c);
        uint16_t tmp[4] = { f2bf(f.x), f2bf(f.y), f2bf(f.z), f2bf(f.w) };
        *(uint2*)&actS[r][c] = *(uint2*)tmp;
    }
    {
        const float4* ob = (const float4*)sa.obs + (size_t)m0 * 64;
        uint2* od = (uint2*)sa.obsb + (size_t)m0 * 64;
#pragma unroll
        for (int j = 0; j < 4; ++j) {
            float4 f = ob[(j << 9) + t];
            uint16_t tmp[4] = { f2bf(f.x), f2bf(f.y), f2bf(f.z), f2bf(f.w) };
            od[(j << 9) + t] = *(uint2*)tmp;
        }
    }
    __syncthreads();
    // x = rms(gelu(action@wenc)) -> LDS T0 + global xb (g1's ln1 residual)
    gemm_enc(m0, &actS[0][0], wenc, sa.xb, &T0[0][0], sa.ln0, rowsum);
    gemm2_ws<EP2_NONE, true>(m0, &T0[0][0], wq, wk, sa.bq, sa.bk, nullptr, red);
    gemm2_ws<EP2_NONE, true>(m0, &T0[0][0], wv, wg, sa.bv, sa.bg, nullptr, red);
}

__global__ __launch_bounds__(512, 4) void attn_k(SegArgs sa, const float* __restrict__ gns,
                                                 const float* __restrict__ gnb)
{
    __shared__ __align__(16) uint16_t QS[256][40];
    __shared__ __align__(16) uint16_t Ks[256][40];
    __shared__ __align__(16) uint16_t Vt[32][264];
    const int b = blockIdx.x & 63, h = blockIdx.x >> 6;
    const float l2g = sa.l2g[h];
    const int t = threadIdx.x, w = t >> 6, lane = t & 63, l16 = lane & 15, lg = lane >> 4;
    const size_t base = ((size_t)b * 256) * 256 + (size_t)h * 32;
    const uint16_t *q = sa.bq, *kbuf = sa.bk, *vbuf = sa.bv, *g = sa.bg;
    uint16_t* out = sa.brg;

    if (t < 256) {
        const uint4* qr = (const uint4*)(q + base + (size_t)t * 256);
        *(uint4*)&QS[t][0] = qr[0]; *(uint4*)&QS[t][8] = qr[1];
        *(uint4*)&QS[t][16] = qr[2]; *(uint4*)&QS[t][24] = qr[3];
        const uint4* kr = (const uint4*)(kbuf + base + (size_t)t * 256);
        *(uint4*)&Ks[t][0] = kr[0]; *(uint4*)&Ks[t][8] = kr[1];
        *(uint4*)&Ks[t][16] = kr[2]; *(uint4*)&Ks[t][24] = kr[3];
    } else {
        int c = t - 256;
        union { uint4 v4[4]; uint16_t u[32]; } vv;
        const uint4* vr = (const uint4*)(vbuf + base + (size_t)c * 256);
        vv.v4[0] = vr[0]; vv.v4[1] = vr[1]; vv.v4[2] = vr[2]; vv.v4[3] = vr[3];
#pragma unroll
        for (int d = 0; d < 32; ++d) Vt[d][c] = vv.u[d];
    }
    __syncthreads();

    // balanced strips: wave w owns 16-row half-strips {w, 15-w} (work sums to 9)
    const int iA = w, iB = 15 - w;
    short8 qFA = *(const short8*)&QS[(iA << 4) + l16][lg << 3];
    short8 qFB = *(const short8*)&QS[(iB << 4) + l16][lg << 3];

    const float invsq = 0.17677669529663687f;

    floatx4 raccA[2], raccB[2];
    raccA[0] = (floatx4){0,0,0,0}; raccA[1] = (floatx4){0,0,0,0};
    raccB[0] = (floatx4){0,0,0,0}; raccB[1] = (floatx4){0,0,0,0};

    auto do_strip = [&](int si, short8 qF, floatx4 (&racc)[2]) {
        const int jtmax = ((si << 4) + 15) >> 5;
        for (int jt = 0; jt <= jtmax; ++jt) {
            const int j0 = jt << 5;
            floatx4 sacc[2];
            sacc[0] = (floatx4){0,0,0,0}; sacc[1] = (floatx4){0,0,0,0};
            short8 kF[2];
#pragma unroll
            for (int ct = 0; ct < 2; ++ct)
                kF[ct] = *(const short8*)&Ks[j0 + (ct << 4) + l16][lg << 3];
#pragma unroll
            for (int ct = 0; ct < 2; ++ct)
                sacc[ct] = __builtin_amdgcn_mfma_f32_16x16x32_bf16(
                    qF, kF[ct], sacc[ct], 0, 0, 0);
#pragma unroll
            for (int ct = 0; ct < 2; ++ct)
#pragma unroll
                for (int r = 0; r < 4; ++r) {
                    int row16 = (lg << 2) + r;
                    int i = (si << 4) + row16;
                    int j = j0 + (ct << 4) + l16;
                    float svv = 0.f;
                    if (i >= j)
                        svv = sacc[ct][r] * invsq *
                              exp2f((float)((i >> 3) - (j >> 3)) * l2g);
                    QS[(si << 4) + row16][(ct << 4) + l16] = f2bf(svv);
                }
            short8 vF[2];
#pragma unroll
            for (int ct = 0; ct < 2; ++ct)
                vF[ct] = *(const short8*)&Vt[(ct << 4) + l16][j0 + (lg << 3)];
            short8 sF = *(const short8*)&QS[(si << 4) + l16][lg << 3];
#pragma unroll
            for (int ct = 0; ct < 2; ++ct)
                racc[ct] = __builtin_amdgcn_mfma_f32_16x16x32_bf16(
                    sF, vF[ct], racc[ct], 0, 0, 0);
        }
    };
    do_strip(iA, qFA, raccA);
    do_strip(iB, qFB, raccB);

    auto epi = [&](int si, floatx4 (&racc)[2]) {
#pragma unroll
        for (int r = 0; r < 4; ++r) {
            float v0 = racc[0][r], v1 = racc[1][r];
            float s1 = v0 + v1, s2 = v0 * v0 + v1 * v1;
            s1 += __shfl_xor(s1, 1, 64); s2 += __shfl_xor(s2, 1, 64);
            s1 += __shfl_xor(s1, 2, 64); s2 += __shfl_xor(s2, 2, 64);
            s1 += __shfl_xor(s1, 4, 64); s2 += __shfl_xor(s2, 4, 64);
            s1 += __shfl_xor(s1, 8, 64); s2 += __shfl_xor(s2, 8, 64);
            float mu = s1 * (1.f / 32.f);
            float var = s2 * (1.f / 32.f) - mu * mu;
            float rstd = rsqrtf(var + 1e-5f);
            int srow = (si << 4) + (lg << 2) + r;
            size_t obase = ((size_t)b * 256 + srow) * 256 + (size_t)h * 32;
#pragma unroll
            for (int ct = 0; ct < 2; ++ct) {
                int d = (ct << 4) + l16;
                float x = ct ? v1 : v0;
                float y = (x - mu) * rstd * gns[h * 32 + d] + gnb[h * 32 + d];
                float gv = swishf(bf2f(g[obase + d]));
                out[obase + d] = f2bf(y * gv);
            }
        }
    };
    epi(iA, raccA);
    epi(iB, raccB);
}

__global__ __launch_bounds__(512, 4) void g1_k(SegArgs sa,
    const uint16_t* __restrict__ wo, const float* __restrict__ ln1,
    const uint16_t* __restrict__ wq, const uint16_t* __restrict__ wk,
    const uint16_t* __restrict__ wv, const uint16_t* __restrict__ wg)
{
    __shared__ float rowsum[8][32];
    __shared__ float red[4][32][64];
    __shared__ __align__(16) uint16_t T0[32][APAD];
    __shared__ __align__(16) uint16_t T1[32][APAD];
    const int m0 = rowbase(blockIdx.x);
    stage32(sa.brg, m0, &T1[0][0]);
    __syncthreads();
    // x1 = rms(x + brg@wo) -> LDS T0 (consumed only by wk/wv)
    gemm_ks<true, false, false, false>(m0, &T1[0][0], wo,
        nullptr, &T0[0][0], nullptr, sa.xb, nullptr, ln1, rowsum, red);
    // T1 free (its reads finished before gemm_ks's exchange barrier): stage obsb
    stage32(sa.obsb, m0, &T1[0][0]);
    gemm2_ws<EP2_NONE, true>(m0, &T0[0][0], wk, wv, sa.bk, sa.bv, nullptr, red);
    __syncthreads();
    gemm2_ws<EP2_NONE, true>(m0, &T1[0][0], wq, wg, sa.bq, sa.bg, nullptr, red);
}

__global__ __launch_bounds__(512, 4) void g2_k(SegArgs sa,
    const uint16_t* __restrict__ wo, const float* __restrict__ ln2,
    const uint16_t* __restrict__ wswg, const uint16_t* __restrict__ wsw1,
    const uint16_t* __restrict__ wsw2, const float* __restrict__ ln3,
    const uint16_t* __restrict__ nwq, const uint16_t* __restrict__ nwk,
    const uint16_t* __restrict__ nwv, const uint16_t* __restrict__ nwg)
{
    __shared__ float rowsum[8][32];
    __shared__ float red[4][32][64];
    __shared__ __align__(16) uint16_t T0[32][APAD];
    __shared__ __align__(16) uint16_t T1[32][APAD];
    const int m0 = rowbase(blockIdx.x);
    stage32(sa.brg, m0, &T1[0][0]);
    __syncthreads();
    // x2 = rms(obs + brg@wo) -> LDS T0
    gemm_ks<true, false, false, false>(m0, &T1[0][0], wo,
        nullptr, &T0[0][0], nullptr, sa.obsb, nullptr, ln2, rowsum, red);
    // swiglu gate*up -> LDS T1 (gate=lo/swg, up=hi/sw1 via red); no trailing barrier
    gemm2_ws<EP2_SWIGLU, true>(m0, &T0[0][0], wswg, wsw1, nullptr, nullptr, &T1[0][0], red);
    __syncthreads();   // T1 visible to all waves
    // x3 = rms(x2 + T1@sw2): T0 in-place (resid rows read by the owning wave
    // pre-rowsum-barrier, rewritten post-barrier by the same thread).
    // Global xb copy for next g1 / head.
    gemm_ks<true, true, true, false>(m0, &T1[0][0], wsw2,
        sa.xb, &T0[0][0], nullptr, nullptr, &T0[0][0], ln3, rowsum, red);
    if (nwq) {
        gemm2_ws<EP2_NONE, true>(m0, &T0[0][0], nwq, nwk, sa.bq, sa.bk, nullptr, red);
        gemm2_ws<EP2_NONE, true>(m0, &T0[0][0], nwv, nwg, sa.bv, sa.bg, nullptr, red);
    }
}

__global__ __launch_bounds__(512, 4) void head_k(SegArgs sa, const uint16_t* __restrict__ hw1t)
{
    __shared__ float rowsum[8][32];
    __shared__ float red[4][32][64];   // reused as w2s after the GEMM
    __shared__ __align__(16) uint16_t T0[32][APAD];
    const int t = threadIdx.x;
    const int m0 = rowbase(blockIdx.x);
    // h = rms(gelu(x@hw1+hb1)) -> LDS T0 (A = xb global)
    gemm_ks<false, false, false, true>(m0, sa.xb, hw1t,
        nullptr, &T0[0][0], sa.hb1, nullptr, nullptr, sa.hln, rowsum, red);
    float* w2s = &red[0][0][0];        // red dead after gemm_ks's final barrier
#pragma unroll
    for (int j = 0; j < 16; ++j) w2s[(j << 9) + t] = sa.hw2[(j << 9) + t];
    __syncthreads();
    {
        int n = t & 31, rs = t >> 5;    // rs 0..15
#pragma unroll
        for (int rr = 0; rr < 2; ++rr) {
            int lrow = (rr << 4) + rs;
            float a0 = sa.hb2[n];
#pragma unroll 8
            for (int kk = 0; kk < 256; ++kk)
                a0 += bf2f(T0[lrow][kk]) * w2s[kk * 32 + n];
            sa.outp[(size_t)(m0 + lrow) * 32 + n] = a0;
        }
    }
}

// ---------------- host ----------------
extern "C" void kernel_launch(void* const* d_in, const int* in_sizes, int n_in,
                              void* d_out, int out_size, void* d_ws, size_t ws_size,
                              hipStream_t stream)
{
    const float* action = (const float*)d_in[0];
    const float* obs    = (const float*)d_in[1];
    const float* w_enc  = (const float*)d_in[2];
    const float* ln0    = (const float*)d_in[3];
    const float* wq1 = (const float*)d_in[4];
    const float* wk1 = (const float*)d_in[5];
    const float* wv1 = (const float*)d_in[6];
    const float* wg1 = (const float*)d_in[7];
    const float* wo1 = (const float*)d_in[8];
    const float* gns1 = (const float*)d_in[9];
    const float* gnb1 = (const float*)d_in[10];
    const float* ln1  = (const float*)d_in[11];
    const float* wq2 = (const float*)d_in[12];
    const float* wk2 = (const float*)d_in[13];
    const float* wv2 = (const float*)d_in[14];
    const float* wg2 = (const float*)d_in[15];
    const float* wo2 = (const float*)d_in[16];
    const float* gns2 = (const float*)d_in[17];
    const float* gnb2 = (const float*)d_in[18];
    const float* ln2  = (const float*)d_in[19];
    const float* swgp = (const float*)d_in[20];
    const float* sw1p = (const float*)d_in[21];
    const float* sw2p = (const float*)d_in[22];
    const float* ln3  = (const float*)d_in[23];
    const float* hw1  = (const float*)d_in[24];
    const float* hb1  = (const float*)d_in[25];
    const float* hln  = (const float*)d_in[26];
    const float* hw2  = (const float*)d_in[27];
    const float* hb2  = (const float*)d_in[28];

    char* ws = (char*)d_ws;
    uint16_t* wt   = (uint16_t*)(ws + 0);
    uint16_t* actb = (uint16_t*)(ws + 6291456);
    uint16_t* obsb = (uint16_t*)(ws + 7340032);
    uint16_t* xb   = (uint16_t*)(ws + 15728640);
    uint16_t* bq   = (uint16_t*)(ws + 24117248);
    uint16_t* bk   = (uint16_t*)(ws + 32505856);
    uint16_t* bv   = (uint16_t*)(ws + 40894464);
    uint16_t* bg   = (uint16_t*)(ws + 49283072);
    uint16_t* brg  = (uint16_t*)(ws + 57671680);

    uint16_t* wtenc = wt;
    uint16_t* hw1t  = wt + CHUNK_E + (size_t)39 * MAT_E;
    auto WTp = [&](int ti, int s) { return wt + CHUNK_E + (size_t)(ti * 3 + s) * MAT_E; };

    TArg ta;
    ta.src[0] = w_enc;
    ta.src[1] = wq1;  ta.src[2] = wk1;  ta.src[3] = wv1;  ta.src[4] = wg1;  ta.src[5] = wo1;
    ta.src[6] = wq2;  ta.src[7] = wk2;  ta.src[8] = wv2;  ta.src[9] = wg2;  ta.src[10] = wo2;
    ta.src[11] = swgp; ta.src[12] = sw1p; ta.src[13] = sw2p; ta.src[14] = hw1;
    tpose_k<<<dim3(4, 8, 41), 256, 0, stream>>>(ta, wt);

    SegArgs sa;
    sa.action = action; sa.obs = obs;
    sa.actb = actb; sa.obsb = obsb; sa.xb = xb;
    sa.bq = bq; sa.bk = bk; sa.bv = bv; sa.bg = bg; sa.brg = brg;
    sa.ln0 = ln0; sa.hb1 = hb1; sa.hln = hln; sa.hw2 = hw2; sa.hb2 = hb2;
    sa.outp = (float*)d_out;
    {
        const double a = log(1.0 / 32.0), bb = log(1.0 / 512.0);
        for (int hh = 0; hh < 8; ++hh) {
            double lg = a + (bb - a) * hh / 7.0;
            double gam = 1.0 - exp(lg);
            sa.l2g[hh] = (float)(log(gam) / log(2.0));
        }
    }

    dim3 GB(512), TB(512);
    seg0_k<<<GB, TB, 0, stream>>>(sa, wtenc, WTp(0, 0), WTp(1, 0), WTp(2, 0), WTp(3, 0));
    for (int b3 = 0; b3 < 3; ++b3) {
        attn_k<<<GB, TB, 0, stream>>>(sa, gns1 + b3 * 256, gnb1 + b3 * 256);
        g1_k<<<GB, TB, 0, stream>>>(sa, WTp(4, b3), ln1 + b3 * 256,
                                    WTp(5, b3), WTp(6, b3), WTp(7, b3), WTp(8, b3));
        attn_k<<<GB, TB, 0, stream>>>(sa, gns2 + b3 * 256, gnb2 + b3 * 256);
        g2_k<<<GB, TB, 0, stream>>>(sa, WTp(9, b3), ln2 + b3 * 256,
                                    WTp(10, b3), WTp(11, b3), WTp(12, b3), ln3 + b3 * 256,
                                    b3 < 2 ? WTp(0, b3 + 1) : nullptr,
                                    b3 < 2 ? WTp(1, b3 + 1) : nullptr,
                                    b3 < 2 ? WTp(2, b3 + 1) : nullptr,
                                    b3 < 2 ? WTp(3, b3 + 1) : nullptr);
    }
    head_k<<<GB, TB, 0, stream>>>(sa, hw1t);
}